// Round 1
// baseline (2488.380 us; speedup 1.0000x reference)
//
#include <hip/hip_runtime.h>

// ---------------------------------------------------------------------------
// Conformer encoder, MI355X bf16-MFMA implementation (round 0: correctness).
// B=8 T=512 D=512 H=8 DK=64 L=4 K=31 DFF=2048.
// All matmuls: bf16 inputs, fp32 accum (mfma_f32_16x16x32_bf16, m97-style
// 128x128 tile, BK=32, global_load_lds staging). Residual stream fp32.
// Rel-shift folded into the BD GEMM epilogue as a diagonal scatter-add.
// ---------------------------------------------------------------------------

typedef unsigned short u16;
typedef unsigned int u32;
typedef __attribute__((ext_vector_type(8))) short bf16x8;
typedef __attribute__((ext_vector_type(4))) float f32x4;

#define DI __device__ __forceinline__

constexpr int CT = 512;     // sequence length T
constexpr int CD = 512;     // model dim D
constexpr int CH = 8;       // heads
constexpr int CDK = 64;     // head dim
constexpr int CDFF = 2048;  // ffn dim
constexpr int CNBT = 4096;  // B*T
constexpr int CL = 4;       // layers

DI u16 f2bf(float f) {
  u32 u = __builtin_bit_cast(u32, f);
  u = u + 0x7fffu + ((u >> 16) & 1u);
  return (u16)(u >> 16);
}
DI float bf2f(u16 h) { u32 u = ((u32)h) << 16; return __builtin_bit_cast(float, u); }
DI u32 pack2(float a, float b) { return (u32)f2bf(a) | ((u32)f2bf(b) << 16); }
DI float sigm(float x) { return 1.0f / (1.0f + __expf(-x)); }

DI void gload16(const void* g, void* l) {
  __builtin_amdgcn_global_load_lds((const __attribute__((address_space(1))) void*)g,
                                   (__attribute__((address_space(3))) void*)l, 16, 0, 0);
}

DI float wsum(float v) {
#pragma unroll
  for (int o = 32; o > 0; o >>= 1) v += __shfl_xor(v, o, 64);
  return v;
}
DI float wmax(float v) {
#pragma unroll
  for (int o = 32; o > 0; o >>= 1) v = fmaxf(v, __shfl_xor(v, o, 64));
  return v;
}

// ------------------------- weight conversion -------------------------------
// fp32 [R,C] -> bf16 [C,R]  (per-z slice, separate in/out z strides)
__global__ __launch_bounds__(256) void tconv_k(const float* __restrict__ in,
                                               u16* __restrict__ out, int R, int C,
                                               long inZ, long outZ) {
  __shared__ float t[32][33];
  int c0 = blockIdx.x * 32, r0 = blockIdx.y * 32;
  const float* ip = in + (long)blockIdx.z * inZ;
  u16* op = out + (long)blockIdx.z * outZ;
#pragma unroll
  for (int i = threadIdx.y; i < 32; i += 8)
    t[i][threadIdx.x] = ip[(long)(r0 + i) * C + c0 + threadIdx.x];
  __syncthreads();
#pragma unroll
  for (int i = threadIdx.y; i < 32; i += 8)
    op[(long)(c0 + i) * R + r0 + threadIdx.x] = f2bf(t[threadIdx.x][i]);
}

// fp32 -> bf16 flat, zero-fill beyond nIn (used to pad pos_emb to 1024 rows)
__global__ __launch_bounds__(256) void cvt_k(const float* __restrict__ in,
                                             u16* __restrict__ out, long nIn, long nOut,
                                             long inZ, long outZ) {
  long i = ((long)blockIdx.x * 256 + threadIdx.x) * 4;
  if (i >= nOut) return;
  const float* ip = in + (long)blockIdx.y * inZ;
  u16* op = out + (long)blockIdx.y * outZ;
  u16 o[4];
#pragma unroll
  for (int j = 0; j < 4; ++j) {
    long idx = i + j;
    o[j] = (idx < nIn) ? f2bf(ip[idx]) : (u16)0;
  }
  uint2 st;
  st.x = (u32)o[0] | ((u32)o[1] << 16);
  st.y = (u32)o[2] | ((u32)o[3] << 16);
  *(uint2*)&op[i] = st;
}

__global__ __launch_bounds__(256) void qkvbias_k(const float* __restrict__ bq,
                                                 const float* __restrict__ bk,
                                                 const float* __restrict__ bv,
                                                 float* __restrict__ out) {
  int z = blockIdx.y;
  int j = blockIdx.x * 256 + threadIdx.x;
  float v;
  if (j < 512) v = bq[z * 512 + j];
  else if (j < 1024) v = bk[z * 512 + j - 512];
  else v = bv[z * 512 + j - 1024];
  out[z * 1536 + j] = v;
}

__global__ __launch_bounds__(256) void copy_k(const float* __restrict__ in,
                                              float* __restrict__ out) {
  long i = ((long)blockIdx.x * 256 + threadIdx.x) * 4;
  *(float4*)(out + i) = *(const float4*)(in + i);
}

// ------------------------------- LayerNorm ---------------------------------
// one wave per row of 512; F32OUT=0 -> bf16 out, 1 -> fp32 out (in==out ok)
template <int F32OUT>
__global__ __launch_bounds__(256) void ln_k(const float* in, void* out,
                                            const float* gw, const float* bw) {
  int tid = threadIdx.x, wid = tid >> 6, lane = tid & 63;
  long row = (long)blockIdx.x * 4 + wid;
  const float* x = in + row * CD + lane * 8;
  float4 v0 = *(const float4*)x;
  float4 v1 = *(const float4*)(x + 4);
  float s = v0.x + v0.y + v0.z + v0.w + v1.x + v1.y + v1.z + v1.w;
  float q = v0.x * v0.x + v0.y * v0.y + v0.z * v0.z + v0.w * v0.w +
            v1.x * v1.x + v1.y * v1.y + v1.z * v1.z + v1.w * v1.w;
  s = wsum(s);
  q = wsum(q);
  float mean = s * (1.0f / CD);
  float var = q * (1.0f / CD) - mean * mean;
  float rs = rsqrtf(var + 1e-5f);
  int c = lane * 8;
  float4 g0 = *(const float4*)(gw + c), g1 = *(const float4*)(gw + c + 4);
  float4 b0 = *(const float4*)(bw + c), b1 = *(const float4*)(bw + c + 4);
  float y0 = (v0.x - mean) * rs * g0.x + b0.x;
  float y1 = (v0.y - mean) * rs * g0.y + b0.y;
  float y2 = (v0.z - mean) * rs * g0.z + b0.z;
  float y3 = (v0.w - mean) * rs * g0.w + b0.w;
  float y4 = (v1.x - mean) * rs * g1.x + b1.x;
  float y5 = (v1.y - mean) * rs * g1.y + b1.y;
  float y6 = (v1.z - mean) * rs * g1.z + b1.z;
  float y7 = (v1.w - mean) * rs * g1.w + b1.w;
  if (F32OUT) {
    float* o = (float*)out + row * CD + c;
    *(float4*)o = make_float4(y0, y1, y2, y3);
    *(float4*)(o + 4) = make_float4(y4, y5, y6, y7);
  } else {
    u16* o = (u16*)out + row * CD + c;
    uint4 pk;
    pk.x = pack2(y0, y1);
    pk.y = pack2(y2, y3);
    pk.z = pack2(y4, y5);
    pk.w = pack2(y6, y7);
    *(uint4*)o = pk;
  }
}

// --------------------------------- GEMM ------------------------------------
// C[m,n] = sum_k A[m,k] * B[n,k]   (A row-major [M,K], B row-major [N,K])
// EPI: 0 store bf16 | 1 +bias bf16 | 2 +bias swish bf16 | 3 res += alpha*(v+bias)
//      4 +bias f32  | 5 store f32  | 6 rel-shift scatter-add f32
// BHZ: blockIdx.z -> (b = z>>3, h = z&7); per-operand (b,h) strides.
template <int BM, int BN, int BK, int WM, int WN, int EPI, bool BHZ>
__global__ __launch_bounds__(256) void gemm_k(
    const u16* __restrict__ A, const u16* __restrict__ B, void* C,
    const float* __restrict__ bias, float alpha, int lda, int ldb, int ldc, int Kd,
    long aSb, long aSh, long bSb, long bSh, long cSb, long cSh) {
  static_assert(BK == 32, "");
  static_assert((BM / WM) * (BN / WN) == 4, "");
  __shared__ u16 ldsA[BM * BK];
  __shared__ u16 ldsB[BN * BK];
  const int tid = threadIdx.x, wid = tid >> 6, lane = tid & 63;
  const int m0 = blockIdx.x * BM, n0 = blockIdx.y * BN;
  if constexpr (EPI == 6) {
    // tile fully outside the valid rel-shift band -> skip
    if (m0 + n0 + 254 < 511 || m0 + n0 > 1022) return;
  }
  long aOff = 0, bOff = 0, cOff = 0;
  if constexpr (BHZ) {
    int zb = blockIdx.z >> 3, zh = blockIdx.z & 7;
    aOff = zb * aSb + zh * aSh;
    bOff = zb * bSb + zh * bSh;
    cOff = zb * cSb + zh * cSh;
  }
  const u16* Ab = A + aOff;
  const u16* Bb = B + bOff;
  constexpr int nWn = BN / WN;
  const int wm = wid / nWn, wn = wid % nWn;
  constexpr int FM = WM / 16, FN = WN / 16;
  const f32x4 vzero = {0.f, 0.f, 0.f, 0.f};
  f32x4 acc[FM][FN];
#pragma unroll
  for (int mi = 0; mi < FM; ++mi)
#pragma unroll
    for (int ni = 0; ni < FN; ++ni) acc[mi][ni] = vzero;

  const int ar = lane & 15, kq = (lane >> 4) * 8;
  constexpr int AR = (BM * BK * 2) / 4096;
  constexpr int BR = (BN * BK * 2) / 4096;

  for (int k0 = 0; k0 < Kd; k0 += BK) {
    __syncthreads();
#pragma unroll
    for (int r = 0; r < AR; ++r) {
      int boff = r * 4096 + tid * 16;
      int row = boff >> 6;           // 64 B per 32-elem bf16 row
      int ke = (boff & 63) >> 1;
      gload16(Ab + (long)(m0 + row) * lda + k0 + ke,
              (char*)ldsA + r * 4096 + wid * 1024);
    }
#pragma unroll
    for (int r = 0; r < BR; ++r) {
      int boff = r * 4096 + tid * 16;
      int row = boff >> 6;
      int ke = (boff & 63) >> 1;
      gload16(Bb + (long)(n0 + row) * ldb + k0 + ke,
              (char*)ldsB + r * 4096 + wid * 1024);
    }
    asm volatile("s_waitcnt vmcnt(0)" ::: "memory");
    __syncthreads();
    bf16x8 af[FM], bfr[FN];
#pragma unroll
    for (int mi = 0; mi < FM; ++mi)
      af[mi] = *(const bf16x8*)&ldsA[(wm * WM + mi * 16 + ar) * BK + kq];
#pragma unroll
    for (int ni = 0; ni < FN; ++ni)
      bfr[ni] = *(const bf16x8*)&ldsB[(wn * WN + ni * 16 + ar) * BK + kq];
#pragma unroll
    for (int mi = 0; mi < FM; ++mi)
#pragma unroll
      for (int ni = 0; ni < FN; ++ni)
        acc[mi][ni] = __builtin_amdgcn_mfma_f32_16x16x32_bf16(af[mi], bfr[ni],
                                                              acc[mi][ni], 0, 0, 0);
  }

#pragma unroll
  for (int mi = 0; mi < FM; ++mi) {
    const int gmB = m0 + wm * WM + mi * 16 + (lane >> 4) * 4;
#pragma unroll
    for (int ni = 0; ni < FN; ++ni) {
      const int gn = n0 + wn * WN + ni * 16 + (lane & 15);
      float bv_ = 0.f;
      if constexpr (EPI == 1 || EPI == 2 || EPI == 3 || EPI == 4) bv_ = bias[gn];
#pragma unroll
      for (int r = 0; r < 4; ++r) {
        const int gm = gmB + r;
        float v = acc[mi][ni][r];
        long idx = cOff + (long)gm * ldc + gn;
        if constexpr (EPI == 0) ((u16*)C)[idx] = f2bf(v);
        else if constexpr (EPI == 1) ((u16*)C)[idx] = f2bf(v + bv_);
        else if constexpr (EPI == 2) {
          float x = v + bv_;
          ((u16*)C)[idx] = f2bf(x * sigm(x));
        } else if constexpr (EPI == 3) {
          float* R = (float*)C;
          R[idx] += alpha * (v + bv_);
        } else if constexpr (EPI == 4) ((float*)C)[idx] = v + bv_;
        else if constexpr (EPI == 5) ((float*)C)[idx] = v;
        else if constexpr (EPI == 6) {
          int s = gn - 511 + gm;   // rel_shift: S[t,s] gets bd[t, s+511-t]
          if (0 <= s && s < 512) ((float*)C)[cOff + (long)gm * ldc + s] += v;
        }
      }
    }
  }
}

// ---------------------------- attention helpers ----------------------------
// qu = q + pbu, qv = q + pbv  (q = first 512 cols of qkv)
__global__ __launch_bounds__(256) void quqv_k(const u16* __restrict__ qkv,
                                              const float* __restrict__ pbu,
                                              const float* __restrict__ pbv,
                                              u16* __restrict__ qu, u16* __restrict__ qv) {
  long i = (long)blockIdx.x * 256 + threadIdx.x;  // 4 elems each
  long r = i >> 7;
  int c = (int)(i & 127) * 4;
  const u16* q = qkv + r * 1536 + c;
  uint2 qq = *(const uint2*)q;
  float f0 = bf2f((u16)(qq.x & 0xffff)), f1 = bf2f((u16)(qq.x >> 16));
  float f2 = bf2f((u16)(qq.y & 0xffff)), f3 = bf2f((u16)(qq.y >> 16));
  float4 bu = *(const float4*)(pbu + c);
  float4 bv = *(const float4*)(pbv + c);
  uint2 ou, ov;
  ou.x = pack2(f0 + bu.x, f1 + bu.y);
  ou.y = pack2(f2 + bu.z, f3 + bu.w);
  ov.x = pack2(f0 + bv.x, f1 + bv.y);
  ov.y = pack2(f2 + bv.z, f3 + bv.w);
  *(uint2*)&qu[r * 512 + c] = ou;
  *(uint2*)&qv[r * 512 + c] = ov;
}

// vt[bh][d][t] = v[b,t,h,d]  (v = cols 1024..1535 of qkv)
__global__ __launch_bounds__(256) void vtrans_k(const u16* __restrict__ qkv,
                                                u16* __restrict__ vt) {
  __shared__ u16 t[64][80];
  int tid = threadIdx.x;
  int t0 = blockIdx.x * 64;
  int bh = blockIdx.y, b = bh >> 3, h = bh & 7;
  {
    int tl = tid >> 2, dg = (tid & 3) * 16;
    const u16* src = qkv + ((long)(b * CT + t0 + tl)) * 1536 + 1024 + h * 64 + dg;
    uint4 a0 = *(const uint4*)src;
    uint4 a1 = *(const uint4*)(src + 8);
    *(uint4*)&t[tl][dg] = a0;
    *(uint4*)&t[tl][dg + 8] = a1;
  }
  __syncthreads();
  {
    int dl = tid >> 2, tg = (tid & 3) * 16;
    u16* dst = vt + ((long)bh * 64 + dl) * CT + t0 + tg;
    u16 tmp[16];
#pragma unroll
    for (int j = 0; j < 16; ++j) tmp[j] = t[tg + j][dl];
    uint4 o0, o1;
    o0.x = (u32)tmp[0] | ((u32)tmp[1] << 16);
    o0.y = (u32)tmp[2] | ((u32)tmp[3] << 16);
    o0.z = (u32)tmp[4] | ((u32)tmp[5] << 16);
    o0.w = (u32)tmp[6] | ((u32)tmp[7] << 16);
    o1.x = (u32)tmp[8] | ((u32)tmp[9] << 16);
    o1.y = (u32)tmp[10] | ((u32)tmp[11] << 16);
    o1.z = (u32)tmp[12] | ((u32)tmp[13] << 16);
    o1.w = (u32)tmp[14] | ((u32)tmp[15] << 16);
    *(uint4*)dst = o0;
    *(uint4*)(dst + 8) = o1;
  }
}

// softmax over s of 0.125*S[row, :512] -> bf16 probs
__global__ __launch_bounds__(256) void softmax_k(const float* __restrict__ S,
                                                 u16* __restrict__ P) {
  int tid = threadIdx.x, wid = tid >> 6, lane = tid & 63;
  long row = (long)blockIdx.x * 4 + wid;
  const float* s = S + row * CT + lane * 8;
  float4 a = *(const float4*)s;
  float4 b = *(const float4*)(s + 4);
  float v[8] = {a.x, a.y, a.z, a.w, b.x, b.y, b.z, b.w};
#pragma unroll
  for (int j = 0; j < 8; ++j) v[j] *= 0.125f;
  float m = v[0];
#pragma unroll
  for (int j = 1; j < 8; ++j) m = fmaxf(m, v[j]);
  m = wmax(m);
  float e[8], sum = 0.f;
#pragma unroll
  for (int j = 0; j < 8; ++j) {
    e[j] = __expf(v[j] - m);
    sum += e[j];
  }
  sum = wsum(sum);
  float inv = 1.0f / sum;
  u16* o = P + row * CT + lane * 8;
  uint4 pk;
  pk.x = pack2(e[0] * inv, e[1] * inv);
  pk.y = pack2(e[2] * inv, e[3] * inv);
  pk.z = pack2(e[4] * inv, e[5] * inv);
  pk.w = pack2(e[6] * inv, e[7] * inv);
  *(uint4*)o = pk;
}

// ------------------------------ conv module --------------------------------
__global__ __launch_bounds__(256) void glu_k(const float* __restrict__ p,
                                             u16* __restrict__ u) {
  long i = (long)blockIdx.x * 256 + threadIdx.x;  // 4 elems each
  long r = i >> 7;
  int c = (int)(i & 127) * 4;
  const float* pr = p + r * 1024;
  float4 a = *(const float4*)(pr + c);
  float4 g = *(const float4*)(pr + 512 + c);
  uint2 o;
  o.x = pack2(a.x * sigm(g.x), a.y * sigm(g.y));
  o.y = pack2(a.z * sigm(g.z), a.w * sigm(g.w));
  *(uint2*)&u[r * 512 + c] = o;
}

// depthwise conv(K=31,pad 15) + dw_b + LN(cln) + swish, one (b,t) row / block
__global__ __launch_bounds__(256) void conv_k(const u16* __restrict__ u,
                                              const float* __restrict__ w,
                                              const float* __restrict__ wb,
                                              const float* __restrict__ cg,
                                              const float* __restrict__ cb,
                                              u16* __restrict__ out) {
  int bt = blockIdx.x, b = bt >> 9, t = bt & 511;
  int tid = threadIdx.x, d0 = tid * 2;
  const u16* ub = u + ((long)b * CT) * CD + d0;
  const float* w0 = w + d0 * 31;
  const float* w1 = w + (d0 + 1) * 31;
  float a0 = 0.f, a1 = 0.f;
#pragma unroll
  for (int k = 0; k < 31; ++k) {
    int tt = t + k - 15;
    if ((unsigned)tt < 512u) {
      u32 pr = *(const u32*)(ub + (long)tt * CD);
      a0 += bf2f((u16)(pr & 0xffff)) * w0[k];
      a1 += bf2f((u16)(pr >> 16)) * w1[k];
    }
  }
  a0 += wb[d0];
  a1 += wb[d0 + 1];
  float s = a0 + a1, q = a0 * a0 + a1 * a1;
  s = wsum(s);
  q = wsum(q);
  __shared__ float red[8];
  int wid = tid >> 6, lane = tid & 63;
  if (lane == 0) {
    red[wid] = s;
    red[4 + wid] = q;
  }
  __syncthreads();
  s = red[0] + red[1] + red[2] + red[3];
  q = red[4] + red[5] + red[6] + red[7];
  float mean = s * (1.f / 512), var = q * (1.f / 512) - mean * mean;
  float rs = rsqrtf(var + 1e-5f);
  float y0 = (a0 - mean) * rs * cg[d0] + cb[d0];
  float y1 = (a1 - mean) * rs * cg[d0 + 1] + cb[d0 + 1];
  y0 = y0 * sigm(y0);
  y1 = y1 * sigm(y1);
  *(u32*)(out + (long)bt * CD + d0) = pack2(y0, y1);
}

// ---------------------------------------------------------------------------
extern "C" void kernel_launch(void* const* d_in, const int* in_sizes, int n_in,
                              void* d_out, int out_size, void* d_ws, size_t ws_size,
                              hipStream_t stream) {
  const float* in_x   = (const float*)d_in[0];
  const float* in_pos = (const float*)d_in[1];
  const float* ln1_g  = (const float*)d_in[2];
  const float* ln1_b  = (const float*)d_in[3];
  const float* ff1_w1 = (const float*)d_in[4];
  const float* ff1_b1 = (const float*)d_in[5];
  const float* ff1_w2 = (const float*)d_in[6];
  const float* ff1_b2 = (const float*)d_in[7];
  const float* lnA_g  = (const float*)d_in[8];
  const float* lnA_b  = (const float*)d_in[9];
  const float* Wq     = (const float*)d_in[10];
  const float* bq     = (const float*)d_in[11];
  const float* Wk     = (const float*)d_in[12];
  const float* bk     = (const float*)d_in[13];
  const float* Wv     = (const float*)d_in[14];
  const float* bv     = (const float*)d_in[15];
  const float* Wo     = (const float*)d_in[16];
  const float* bo     = (const float*)d_in[17];
  const float* Wpos   = (const float*)d_in[18];
  const float* pbu    = (const float*)d_in[19];
  const float* pbv    = (const float*)d_in[20];
  const float* lnC_g  = (const float*)d_in[21];
  const float* lnC_b  = (const float*)d_in[22];
  const float* pw1_w  = (const float*)d_in[23];
  const float* pw1_b  = (const float*)d_in[24];
  const float* dw_w   = (const float*)d_in[25];
  const float* dw_b   = (const float*)d_in[26];
  const float* cln_g  = (const float*)d_in[27];
  const float* cln_b  = (const float*)d_in[28];
  const float* pw2_w  = (const float*)d_in[29];
  const float* pw2_b  = (const float*)d_in[30];
  const float* ln2_g  = (const float*)d_in[31];
  const float* ln2_b  = (const float*)d_in[32];
  const float* ff2_w1 = (const float*)d_in[33];
  const float* ff2_b1 = (const float*)d_in[34];
  const float* ff2_w2 = (const float*)d_in[35];
  const float* ff2_b2 = (const float*)d_in[36];
  const float* lnO_g  = (const float*)d_in[37];
  const float* lnO_b  = (const float*)d_in[38];
  (void)in_sizes; (void)n_in; (void)out_size; (void)ws_size;

  char* ws = (char*)d_ws;
  size_t off = 0;
  auto alloc = [&](size_t bytes) -> void* {
    off = (off + 255) & ~(size_t)255;
    void* p = ws + off;
    off += bytes;
    return p;
  };

  // weights (bf16, [N,K] layout) — total ws use ~216 MB
  u16* wt_ff1w1 = (u16*)alloc((size_t)CL * CDFF * CD * 2);
  u16* wt_ff1w2 = (u16*)alloc((size_t)CL * CD * CDFF * 2);
  u16* wt_qkv   = (u16*)alloc((size_t)CL * 1536 * CD * 2);
  u16* wt_o     = (u16*)alloc((size_t)CL * CD * CD * 2);
  u16* wt_pos   = (u16*)alloc((size_t)CL * CD * CD * 2);
  u16* w_pw1    = (u16*)alloc((size_t)CL * 1024 * CD * 2);
  u16* w_pw2    = (u16*)alloc((size_t)CL * CD * CD * 2);
  u16* wt_ff2w1 = (u16*)alloc((size_t)CL * CDFF * CD * 2);
  u16* wt_ff2w2 = (u16*)alloc((size_t)CL * CD * CDFF * 2);
  float* qkvbias = (float*)alloc((size_t)CL * 1536 * 4);
  u16* posbf = (u16*)alloc((size_t)1024 * CD * 2);
  // activations
  float* cur = (float*)alloc((size_t)CNBT * CD * 4);
  u16* ybf   = (u16*)alloc((size_t)CNBT * CD * 2);
  u16* qkv   = (u16*)alloc((size_t)CNBT * 1536 * 2);
  u16* hbf   = (u16*)alloc((size_t)CNBT * CDFF * 2);  // also pw1out f32 [4096,1024]
  u16* qu    = (u16*)alloc((size_t)CNBT * CD * 2);
  u16* qv    = (u16*)alloc((size_t)CNBT * CD * 2);
  u16* pbf   = (u16*)alloc((size_t)1024 * CD * 2);
  u16* vt    = (u16*)alloc((size_t)64 * CDK * CT * 2);
  float* S   = (float*)alloc((size_t)64 * CT * CT * 4);
  u16* probs = (u16*)alloc((size_t)64 * CT * CT * 2);
  u16* obf   = (u16*)alloc((size_t)CNBT * CD * 2);
  u16* ubuf  = (u16*)alloc((size_t)CNBT * CD * 2);
  u16* cbf   = (u16*)alloc((size_t)CNBT * CD * 2);

  dim3 b256(256);
  dim3 tb(32, 8);

  // ---- weight conversion (every call; deterministic) ----
  tconv_k<<<dim3(CDFF / 32, CD / 32, CL), tb, 0, stream>>>(ff1_w1, wt_ff1w1, CD, CDFF,
                                                           (long)CD * CDFF, (long)CDFF * CD);
  tconv_k<<<dim3(CD / 32, CDFF / 32, CL), tb, 0, stream>>>(ff1_w2, wt_ff1w2, CDFF, CD,
                                                           (long)CDFF * CD, (long)CD * CDFF);
  tconv_k<<<dim3(CD / 32, CD / 32, CL), tb, 0, stream>>>(Wq, wt_qkv, CD, CD,
                                                         (long)CD * CD, 1536L * CD);
  tconv_k<<<dim3(CD / 32, CD / 32, CL), tb, 0, stream>>>(Wk, wt_qkv + 512 * 512, CD, CD,
                                                         (long)CD * CD, 1536L * CD);
  tconv_k<<<dim3(CD / 32, CD / 32, CL), tb, 0, stream>>>(Wv, wt_qkv + 1024 * 512, CD, CD,
                                                         (long)CD * CD, 1536L * CD);
  tconv_k<<<dim3(CD / 32, CD / 32, CL), tb, 0, stream>>>(Wo, wt_o, CD, CD,
                                                         (long)CD * CD, (long)CD * CD);
  tconv_k<<<dim3(CD / 32, CD / 32, CL), tb, 0, stream>>>(Wpos, wt_pos, CD, CD,
                                                         (long)CD * CD, (long)CD * CD);
  tconv_k<<<dim3(CDFF / 32, CD / 32, CL), tb, 0, stream>>>(ff2_w1, wt_ff2w1, CD, CDFF,
                                                           (long)CD * CDFF, (long)CDFF * CD);
  tconv_k<<<dim3(CD / 32, CDFF / 32, CL), tb, 0, stream>>>(ff2_w2, wt_ff2w2, CDFF, CD,
                                                           (long)CDFF * CD, (long)CD * CDFF);
  cvt_k<<<dim3(512, CL, 1), b256, 0, stream>>>(pw1_w, w_pw1, 1024L * 512, 1024L * 512,
                                               1024L * 512, 1024L * 512);
  cvt_k<<<dim3(256, CL, 1), b256, 0, stream>>>(pw2_w, w_pw2, 512L * 512, 512L * 512,
                                               512L * 512, 512L * 512);
  cvt_k<<<dim3(512, 1, 1), b256, 0, stream>>>(in_pos, posbf, 1023L * 512, 1024L * 512, 0, 0);
  qkvbias_k<<<dim3(6, CL), b256, 0, stream>>>(bq, bk, bv, qkvbias);
  copy_k<<<dim3(2048), b256, 0, stream>>>(in_x, cur);

  for (int i = 0; i < CL; ++i) {
    const u16* Wf1 = wt_ff1w1 + (long)i * CDFF * CD;
    const u16* Wf2 = wt_ff1w2 + (long)i * CD * CDFF;
    const u16* Wqk = wt_qkv + (long)i * 1536 * CD;
    const u16* Wou = wt_o + (long)i * CD * CD;
    const u16* Wps = wt_pos + (long)i * CD * CD;
    const u16* Wp1 = w_pw1 + (long)i * 1024 * CD;
    const u16* Wp2 = w_pw2 + (long)i * CD * CD;
    const u16* Wf3 = wt_ff2w1 + (long)i * CDFF * CD;
    const u16* Wf4 = wt_ff2w2 + (long)i * CD * CDFF;

    // ---- FFN1 (half residual) ----
    ln_k<0><<<dim3(1024), b256, 0, stream>>>(cur, ybf, ln1_g + i * CD, ln1_b + i * CD);
    gemm_k<128, 128, 32, 64, 64, 2, false><<<dim3(32, 16, 1), b256, 0, stream>>>(
        ybf, Wf1, hbf, ff1_b1 + (long)i * CDFF, 0.f, CD, CD, CDFF, CD, 0, 0, 0, 0, 0, 0);
    gemm_k<128, 128, 32, 64, 64, 3, false><<<dim3(32, 4, 1), b256, 0, stream>>>(
        hbf, Wf2, cur, ff1_b2 + i * CD, 0.5f, CDFF, CDFF, CD, CDFF, 0, 0, 0, 0, 0, 0);

    // ---- rel-pos MHSA ----
    ln_k<0><<<dim3(1024), b256, 0, stream>>>(cur, ybf, lnA_g + i * CD, lnA_b + i * CD);
    gemm_k<128, 128, 32, 64, 64, 1, false><<<dim3(32, 12, 1), b256, 0, stream>>>(
        ybf, Wqk, qkv, qkvbias + i * 1536, 0.f, CD, CD, 1536, CD, 0, 0, 0, 0, 0, 0);
    gemm_k<128, 128, 32, 64, 64, 0, false><<<dim3(8, 4, 1), b256, 0, stream>>>(
        posbf, Wps, pbf, nullptr, 0.f, CD, CD, CD, CD, 0, 0, 0, 0, 0, 0);
    quqv_k<<<dim3(2048), b256, 0, stream>>>(qkv, pbu + i * 512, pbv + i * 512, qu, qv);
    vtrans_k<<<dim3(8, 64), b256, 0, stream>>>(qkv, vt);
    // AC: S[bh][t][s] = qu . k
    gemm_k<128, 128, 32, 64, 64, 5, true><<<dim3(4, 4, 64), b256, 0, stream>>>(
        qu, qkv + 512, S, nullptr, 0.f, 512, 1536, 512, 64,
        (long)CT * CD, 64, (long)CT * 1536, 64, (long)CH * CT * CT, (long)CT * CT);
    // BD: S[bh][t][j-511+t] += qv . p_j
    gemm_k<128, 128, 32, 64, 64, 6, true><<<dim3(4, 8, 64), b256, 0, stream>>>(
        qv, pbf, S, nullptr, 0.f, 512, 512, 512, 64,
        (long)CT * CD, 64, 0, 64, (long)CH * CT * CT, (long)CT * CT);
    softmax_k<<<dim3(8192), b256, 0, stream>>>(S, probs);
    // PV: o[b,t,h,d] = probs . vt
    gemm_k<128, 64, 32, 64, 32, 0, true><<<dim3(4, 1, 64), b256, 0, stream>>>(
        probs, vt, obf, nullptr, 0.f, 512, 512, 512, 512,
        (long)CH * CT * CT, (long)CT * CT, (long)CH * CDK * CT, (long)CDK * CT,
        (long)CT * CD, 64);
    gemm_k<128, 128, 32, 64, 64, 3, false><<<dim3(32, 4, 1), b256, 0, stream>>>(
        obf, Wou, cur, bo + i * CD, 1.0f, CD, CD, CD, CD, 0, 0, 0, 0, 0, 0);

    // ---- conv module ----
    ln_k<0><<<dim3(1024), b256, 0, stream>>>(cur, ybf, lnC_g + i * CD, lnC_b + i * CD);
    gemm_k<128, 128, 32, 64, 64, 4, false><<<dim3(32, 8, 1), b256, 0, stream>>>(
        ybf, Wp1, hbf, pw1_b + (long)i * 1024, 0.f, CD, CD, 1024, CD, 0, 0, 0, 0, 0, 0);
    glu_k<<<dim3(2048), b256, 0, stream>>>((const float*)hbf, ubuf);
    conv_k<<<dim3(4096), b256, 0, stream>>>(ubuf, dw_w + (long)i * 512 * 31, dw_b + i * 512,
                                            cln_g + i * CD, cln_b + i * CD, cbf);
    gemm_k<128, 128, 32, 64, 64, 3, false><<<dim3(32, 4, 1), b256, 0, stream>>>(
        cbf, Wp2, cur, pw2_b + i * CD, 1.0f, CD, CD, CD, CD, 0, 0, 0, 0, 0, 0);

    // ---- FFN2 (half residual) ----
    ln_k<0><<<dim3(1024), b256, 0, stream>>>(cur, ybf, ln2_g + i * CD, ln2_b + i * CD);
    gemm_k<128, 128, 32, 64, 64, 2, false><<<dim3(32, 16, 1), b256, 0, stream>>>(
        ybf, Wf3, hbf, ff2_b1 + (long)i * CDFF, 0.f, CD, CD, CDFF, CD, 0, 0, 0, 0, 0, 0);
    gemm_k<128, 128, 32, 64, 64, 3, false><<<dim3(32, 4, 1), b256, 0, stream>>>(
        hbf, Wf4, cur, ff2_b2 + i * CD, 0.5f, CDFF, CDFF, CD, CDFF, 0, 0, 0, 0, 0, 0);

    // ---- output LN ----
    if (i < CL - 1)
      ln_k<1><<<dim3(1024), b256, 0, stream>>>(cur, cur, lnO_g + i * CD, lnO_b + i * CD);
    else
      ln_k<1><<<dim3(1024), b256, 0, stream>>>(cur, d_out, lnO_g + i * CD, lnO_b + i * CD);
  }
}

// Round 2
// 1755.093 us; speedup vs baseline: 1.4178x; 1.4178x over previous
//
#include <hip/hip_runtime.h>

// ---------------------------------------------------------------------------
// Conformer encoder, MI355X bf16-MFMA implementation.
// Round 1: replace VMEM-issue-bound depthwise conv (208us) with a
// register-strip version (~10us): thread owns 2 channels x 8 time steps,
// input strip held in registers, weights pre-transposed to [31][512].
// ---------------------------------------------------------------------------

typedef unsigned short u16;
typedef unsigned int u32;
typedef __attribute__((ext_vector_type(8))) short bf16x8;
typedef __attribute__((ext_vector_type(4))) float f32x4;

#define DI __device__ __forceinline__

constexpr int CT = 512;     // sequence length T
constexpr int CD = 512;     // model dim D
constexpr int CH = 8;       // heads
constexpr int CDK = 64;     // head dim
constexpr int CDFF = 2048;  // ffn dim
constexpr int CNBT = 4096;  // B*T
constexpr int CL = 4;       // layers

DI u16 f2bf(float f) {
  u32 u = __builtin_bit_cast(u32, f);
  u = u + 0x7fffu + ((u >> 16) & 1u);
  return (u16)(u >> 16);
}
DI float bf2f(u16 h) { u32 u = ((u32)h) << 16; return __builtin_bit_cast(float, u); }
DI u32 pack2(float a, float b) { return (u32)f2bf(a) | ((u32)f2bf(b) << 16); }
DI float sigm(float x) { return 1.0f / (1.0f + __expf(-x)); }

DI void gload16(const void* g, void* l) {
  __builtin_amdgcn_global_load_lds((const __attribute__((address_space(1))) void*)g,
                                   (__attribute__((address_space(3))) void*)l, 16, 0, 0);
}

DI float wsum(float v) {
#pragma unroll
  for (int o = 32; o > 0; o >>= 1) v += __shfl_xor(v, o, 64);
  return v;
}
DI float wmax(float v) {
#pragma unroll
  for (int o = 32; o > 0; o >>= 1) v = fmaxf(v, __shfl_xor(v, o, 64));
  return v;
}

// ------------------------- weight conversion -------------------------------
// fp32 [R,C] -> bf16 [C,R]  (per-z slice, separate in/out z strides)
__global__ __launch_bounds__(256) void tconv_k(const float* __restrict__ in,
                                               u16* __restrict__ out, int R, int C,
                                               long inZ, long outZ) {
  __shared__ float t[32][33];
  int c0 = blockIdx.x * 32, r0 = blockIdx.y * 32;
  const float* ip = in + (long)blockIdx.z * inZ;
  u16* op = out + (long)blockIdx.z * outZ;
#pragma unroll
  for (int i = threadIdx.y; i < 32; i += 8)
    t[i][threadIdx.x] = ip[(long)(r0 + i) * C + c0 + threadIdx.x];
  __syncthreads();
#pragma unroll
  for (int i = threadIdx.y; i < 32; i += 8)
    op[(long)(c0 + i) * R + r0 + threadIdx.x] = f2bf(t[threadIdx.x][i]);
}

// fp32 -> bf16 flat, zero-fill beyond nIn (used to pad pos_emb to 1024 rows)
__global__ __launch_bounds__(256) void cvt_k(const float* __restrict__ in,
                                             u16* __restrict__ out, long nIn, long nOut,
                                             long inZ, long outZ) {
  long i = ((long)blockIdx.x * 256 + threadIdx.x) * 4;
  if (i >= nOut) return;
  const float* ip = in + (long)blockIdx.y * inZ;
  u16* op = out + (long)blockIdx.y * outZ;
  u16 o[4];
#pragma unroll
  for (int j = 0; j < 4; ++j) {
    long idx = i + j;
    o[j] = (idx < nIn) ? f2bf(ip[idx]) : (u16)0;
  }
  uint2 st;
  st.x = (u32)o[0] | ((u32)o[1] << 16);
  st.y = (u32)o[2] | ((u32)o[3] << 16);
  *(uint2*)&op[i] = st;
}

// dw_w [L][512][31] -> wT [L][31][512] fp32
__global__ __launch_bounds__(256) void dwt_k(const float* __restrict__ in,
                                             float* __restrict__ out) {
  int l = blockIdx.y;
  int idx = blockIdx.x * 256 + threadIdx.x;
  if (idx >= 512 * 31) return;
  int k = idx >> 9, d = idx & 511;
  out[(long)l * 31 * 512 + idx] = in[(long)l * 512 * 31 + d * 31 + k];
}

__global__ __launch_bounds__(256) void qkvbias_k(const float* __restrict__ bq,
                                                 const float* __restrict__ bk,
                                                 const float* __restrict__ bv,
                                                 float* __restrict__ out) {
  int z = blockIdx.y;
  int j = blockIdx.x * 256 + threadIdx.x;
  float v;
  if (j < 512) v = bq[z * 512 + j];
  else if (j < 1024) v = bk[z * 512 + j - 512];
  else v = bv[z * 512 + j - 1024];
  out[z * 1536 + j] = v;
}

__global__ __launch_bounds__(256) void copy_k(const float* __restrict__ in,
                                              float* __restrict__ out) {
  long i = ((long)blockIdx.x * 256 + threadIdx.x) * 4;
  *(float4*)(out + i) = *(const float4*)(in + i);
}

// ------------------------------- LayerNorm ---------------------------------
// one wave per row of 512; F32OUT=0 -> bf16 out, 1 -> fp32 out (in==out ok)
template <int F32OUT>
__global__ __launch_bounds__(256) void ln_k(const float* in, void* out,
                                            const float* gw, const float* bw) {
  int tid = threadIdx.x, wid = tid >> 6, lane = tid & 63;
  long row = (long)blockIdx.x * 4 + wid;
  const float* x = in + row * CD + lane * 8;
  float4 v0 = *(const float4*)x;
  float4 v1 = *(const float4*)(x + 4);
  float s = v0.x + v0.y + v0.z + v0.w + v1.x + v1.y + v1.z + v1.w;
  float q = v0.x * v0.x + v0.y * v0.y + v0.z * v0.z + v0.w * v0.w +
            v1.x * v1.x + v1.y * v1.y + v1.z * v1.z + v1.w * v1.w;
  s = wsum(s);
  q = wsum(q);
  float mean = s * (1.0f / CD);
  float var = q * (1.0f / CD) - mean * mean;
  float rs = rsqrtf(var + 1e-5f);
  int c = lane * 8;
  float4 g0 = *(const float4*)(gw + c), g1 = *(const float4*)(gw + c + 4);
  float4 b0 = *(const float4*)(bw + c), b1 = *(const float4*)(bw + c + 4);
  float y0 = (v0.x - mean) * rs * g0.x + b0.x;
  float y1 = (v0.y - mean) * rs * g0.y + b0.y;
  float y2 = (v0.z - mean) * rs * g0.z + b0.z;
  float y3 = (v0.w - mean) * rs * g0.w + b0.w;
  float y4 = (v1.x - mean) * rs * g1.x + b1.x;
  float y5 = (v1.y - mean) * rs * g1.y + b1.y;
  float y6 = (v1.z - mean) * rs * g1.z + b1.z;
  float y7 = (v1.w - mean) * rs * g1.w + b1.w;
  if (F32OUT) {
    float* o = (float*)out + row * CD + c;
    *(float4*)o = make_float4(y0, y1, y2, y3);
    *(float4*)(o + 4) = make_float4(y4, y5, y6, y7);
  } else {
    u16* o = (u16*)out + row * CD + c;
    uint4 pk;
    pk.x = pack2(y0, y1);
    pk.y = pack2(y2, y3);
    pk.z = pack2(y4, y5);
    pk.w = pack2(y6, y7);
    *(uint4*)o = pk;
  }
}

// --------------------------------- GEMM ------------------------------------
// C[m,n] = sum_k A[m,k] * B[n,k]   (A row-major [M,K], B row-major [N,K])
// EPI: 0 store bf16 | 1 +bias bf16 | 2 +bias swish bf16 | 3 res += alpha*(v+bias)
//      4 +bias f32  | 5 store f32  | 6 rel-shift scatter-add f32
// BHZ: blockIdx.z -> (b = z>>3, h = z&7); per-operand (b,h) strides.
template <int BM, int BN, int BK, int WM, int WN, int EPI, bool BHZ>
__global__ __launch_bounds__(256) void gemm_k(
    const u16* __restrict__ A, const u16* __restrict__ B, void* C,
    const float* __restrict__ bias, float alpha, int lda, int ldb, int ldc, int Kd,
    long aSb, long aSh, long bSb, long bSh, long cSb, long cSh) {
  static_assert(BK == 32, "");
  static_assert((BM / WM) * (BN / WN) == 4, "");
  __shared__ u16 ldsA[BM * BK];
  __shared__ u16 ldsB[BN * BK];
  const int tid = threadIdx.x, wid = tid >> 6, lane = tid & 63;
  const int m0 = blockIdx.x * BM, n0 = blockIdx.y * BN;
  if constexpr (EPI == 6) {
    // tile fully outside the valid rel-shift band -> skip
    if (m0 + n0 + 254 < 511 || m0 + n0 > 1022) return;
  }
  long aOff = 0, bOff = 0, cOff = 0;
  if constexpr (BHZ) {
    int zb = blockIdx.z >> 3, zh = blockIdx.z & 7;
    aOff = zb * aSb + zh * aSh;
    bOff = zb * bSb + zh * bSh;
    cOff = zb * cSb + zh * cSh;
  }
  const u16* Ab = A + aOff;
  const u16* Bb = B + bOff;
  constexpr int nWn = BN / WN;
  const int wm = wid / nWn, wn = wid % nWn;
  constexpr int FM = WM / 16, FN = WN / 16;
  const f32x4 vzero = {0.f, 0.f, 0.f, 0.f};
  f32x4 acc[FM][FN];
#pragma unroll
  for (int mi = 0; mi < FM; ++mi)
#pragma unroll
    for (int ni = 0; ni < FN; ++ni) acc[mi][ni] = vzero;

  const int ar = lane & 15, kq = (lane >> 4) * 8;
  constexpr int AR = (BM * BK * 2) / 4096;
  constexpr int BR = (BN * BK * 2) / 4096;

  for (int k0 = 0; k0 < Kd; k0 += BK) {
    __syncthreads();
#pragma unroll
    for (int r = 0; r < AR; ++r) {
      int boff = r * 4096 + tid * 16;
      int row = boff >> 6;           // 64 B per 32-elem bf16 row
      int ke = (boff & 63) >> 1;
      gload16(Ab + (long)(m0 + row) * lda + k0 + ke,
              (char*)ldsA + r * 4096 + wid * 1024);
    }
#pragma unroll
    for (int r = 0; r < BR; ++r) {
      int boff = r * 4096 + tid * 16;
      int row = boff >> 6;
      int ke = (boff & 63) >> 1;
      gload16(Bb + (long)(n0 + row) * ldb + k0 + ke,
              (char*)ldsB + r * 4096 + wid * 1024);
    }
    asm volatile("s_waitcnt vmcnt(0)" ::: "memory");
    __syncthreads();
    bf16x8 af[FM], bfr[FN];
#pragma unroll
    for (int mi = 0; mi < FM; ++mi)
      af[mi] = *(const bf16x8*)&ldsA[(wm * WM + mi * 16 + ar) * BK + kq];
#pragma unroll
    for (int ni = 0; ni < FN; ++ni)
      bfr[ni] = *(const bf16x8*)&ldsB[(wn * WN + ni * 16 + ar) * BK + kq];
#pragma unroll
    for (int mi = 0; mi < FM; ++mi)
#pragma unroll
      for (int ni = 0; ni < FN; ++ni)
        acc[mi][ni] = __builtin_amdgcn_mfma_f32_16x16x32_bf16(af[mi], bfr[ni],
                                                              acc[mi][ni], 0, 0, 0);
  }

#pragma unroll
  for (int mi = 0; mi < FM; ++mi) {
    const int gmB = m0 + wm * WM + mi * 16 + (lane >> 4) * 4;
#pragma unroll
    for (int ni = 0; ni < FN; ++ni) {
      const int gn = n0 + wn * WN + ni * 16 + (lane & 15);
      float bv_ = 0.f;
      if constexpr (EPI == 1 || EPI == 2 || EPI == 3 || EPI == 4) bv_ = bias[gn];
#pragma unroll
      for (int r = 0; r < 4; ++r) {
        const int gm = gmB + r;
        float v = acc[mi][ni][r];
        long idx = cOff + (long)gm * ldc + gn;
        if constexpr (EPI == 0) ((u16*)C)[idx] = f2bf(v);
        else if constexpr (EPI == 1) ((u16*)C)[idx] = f2bf(v + bv_);
        else if constexpr (EPI == 2) {
          float x = v + bv_;
          ((u16*)C)[idx] = f2bf(x * sigm(x));
        } else if constexpr (EPI == 3) {
          float* R = (float*)C;
          R[idx] += alpha * (v + bv_);
        } else if constexpr (EPI == 4) ((float*)C)[idx] = v + bv_;
        else if constexpr (EPI == 5) ((float*)C)[idx] = v;
        else if constexpr (EPI == 6) {
          int s = gn - 511 + gm;   // rel_shift: S[t,s] gets bd[t, s+511-t]
          if (0 <= s && s < 512) ((float*)C)[cOff + (long)gm * ldc + s] += v;
        }
      }
    }
  }
}

// ---------------------------- attention helpers ----------------------------
// qu = q + pbu, qv = q + pbv  (q = first 512 cols of qkv)
__global__ __launch_bounds__(256) void quqv_k(const u16* __restrict__ qkv,
                                              const float* __restrict__ pbu,
                                              const float* __restrict__ pbv,
                                              u16* __restrict__ qu, u16* __restrict__ qv) {
  long i = (long)blockIdx.x * 256 + threadIdx.x;  // 4 elems each
  long r = i >> 7;
  int c = (int)(i & 127) * 4;
  const u16* q = qkv + r * 1536 + c;
  uint2 qq = *(const uint2*)q;
  float f0 = bf2f((u16)(qq.x & 0xffff)), f1 = bf2f((u16)(qq.x >> 16));
  float f2 = bf2f((u16)(qq.y & 0xffff)), f3 = bf2f((u16)(qq.y >> 16));
  float4 bu = *(const float4*)(pbu + c);
  float4 bv = *(const float4*)(pbv + c);
  uint2 ou, ov;
  ou.x = pack2(f0 + bu.x, f1 + bu.y);
  ou.y = pack2(f2 + bu.z, f3 + bu.w);
  ov.x = pack2(f0 + bv.x, f1 + bv.y);
  ov.y = pack2(f2 + bv.z, f3 + bv.w);
  *(uint2*)&qu[r * 512 + c] = ou;
  *(uint2*)&qv[r * 512 + c] = ov;
}

// vt[bh][d][t] = v[b,t,h,d]  (v = cols 1024..1535 of qkv)
__global__ __launch_bounds__(256) void vtrans_k(const u16* __restrict__ qkv,
                                                u16* __restrict__ vt) {
  __shared__ u16 t[64][80];
  int tid = threadIdx.x;
  int t0 = blockIdx.x * 64;
  int bh = blockIdx.y, b = bh >> 3, h = bh & 7;
  {
    int tl = tid >> 2, dg = (tid & 3) * 16;
    const u16* src = qkv + ((long)(b * CT + t0 + tl)) * 1536 + 1024 + h * 64 + dg;
    uint4 a0 = *(const uint4*)src;
    uint4 a1 = *(const uint4*)(src + 8);
    *(uint4*)&t[tl][dg] = a0;
    *(uint4*)&t[tl][dg + 8] = a1;
  }
  __syncthreads();
  {
    int dl = tid >> 2, tg = (tid & 3) * 16;
    u16* dst = vt + ((long)bh * 64 + dl) * CT + t0 + tg;
    u16 tmp[16];
#pragma unroll
    for (int j = 0; j < 16; ++j) tmp[j] = t[tg + j][dl];
    uint4 o0, o1;
    o0.x = (u32)tmp[0] | ((u32)tmp[1] << 16);
    o0.y = (u32)tmp[2] | ((u32)tmp[3] << 16);
    o0.z = (u32)tmp[4] | ((u32)tmp[5] << 16);
    o0.w = (u32)tmp[6] | ((u32)tmp[7] << 16);
    o1.x = (u32)tmp[8] | ((u32)tmp[9] << 16);
    o1.y = (u32)tmp[10] | ((u32)tmp[11] << 16);
    o1.z = (u32)tmp[12] | ((u32)tmp[13] << 16);
    o1.w = (u32)tmp[14] | ((u32)tmp[15] << 16);
    *(uint4*)dst = o0;
    *(uint4*)(dst + 8) = o1;
  }
}

// softmax over s of 0.125*S[row, :512] -> bf16 probs
__global__ __launch_bounds__(256) void softmax_k(const float* __restrict__ S,
                                                 u16* __restrict__ P) {
  int tid = threadIdx.x, wid = tid >> 6, lane = tid & 63;
  long row = (long)blockIdx.x * 4 + wid;
  const float* s = S + row * CT + lane * 8;
  float4 a = *(const float4*)s;
  float4 b = *(const float4*)(s + 4);
  float v[8] = {a.x, a.y, a.z, a.w, b.x, b.y, b.z, b.w};
#pragma unroll
  for (int j = 0; j < 8; ++j) v[j] *= 0.125f;
  float m = v[0];
#pragma unroll
  for (int j = 1; j < 8; ++j) m = fmaxf(m, v[j]);
  m = wmax(m);
  float e[8], sum = 0.f;
#pragma unroll
  for (int j = 0; j < 8; ++j) {
    e[j] = __expf(v[j] - m);
    sum += e[j];
  }
  sum = wsum(sum);
  float inv = 1.0f / sum;
  u16* o = P + row * CT + lane * 8;
  uint4 pk;
  pk.x = pack2(e[0] * inv, e[1] * inv);
  pk.y = pack2(e[2] * inv, e[3] * inv);
  pk.z = pack2(e[4] * inv, e[5] * inv);
  pk.w = pack2(e[6] * inv, e[7] * inv);
  *(uint4*)o = pk;
}

// ------------------------------ conv module --------------------------------
__global__ __launch_bounds__(256) void glu_k(const float* __restrict__ p,
                                             u16* __restrict__ u) {
  long i = (long)blockIdx.x * 256 + threadIdx.x;  // 4 elems each
  long r = i >> 7;
  int c = (int)(i & 127) * 4;
  const float* pr = p + r * 1024;
  float4 a = *(const float4*)(pr + c);
  float4 g = *(const float4*)(pr + 512 + c);
  uint2 o;
  o.x = pack2(a.x * sigm(g.x), a.y * sigm(g.y));
  o.y = pack2(a.z * sigm(g.z), a.w * sigm(g.w));
  *(uint2*)&u[r * 512 + c] = o;
}

// depthwise conv(K=31,pad 15) + dw_b + LN(cln) + swish.
// block = (t-tile of 8, b); thread owns channels (2*tid, 2*tid+1) x 8 t's.
// Input strip held in registers; weights pre-transposed to [31][512].
__global__ __launch_bounds__(256) void conv2_k(const u16* __restrict__ u,
                                               const float* __restrict__ wT,
                                               const float* __restrict__ wb,
                                               const float* __restrict__ cg,
                                               const float* __restrict__ cb,
                                               u16* __restrict__ out) {
  constexpr int TT = 8;
  int tid = threadIdx.x, d0 = tid * 2;
  int b = blockIdx.y, t0 = blockIdx.x * TT;
  const u16* ub = u + ((long)b * CT) * CD + d0;

  u32 strip[TT + 30];
#pragma unroll
  for (int j = 0; j < TT + 30; ++j) {
    int tt = t0 + j - 15;
    strip[j] = ((unsigned)tt < (unsigned)CT) ? *(const u32*)(ub + (long)tt * CD) : 0u;
  }
  float2 bias = *(const float2*)(wb + d0);
  float a0[TT], a1[TT];
#pragma unroll
  for (int t = 0; t < TT; ++t) { a0[t] = bias.x; a1[t] = bias.y; }
#pragma unroll
  for (int k = 0; k < 31; ++k) {
    float2 wk = *(const float2*)(wT + k * CD + d0);
#pragma unroll
    for (int t = 0; t < TT; ++t) {
      u32 pr = strip[t + k];
      a0[t] += bf2f((u16)(pr & 0xffff)) * wk.x;
      a1[t] += bf2f((u16)(pr >> 16)) * wk.y;
    }
  }
  // LayerNorm over channels for each t, then swish
  __shared__ float redS[4][TT], redQ[4][TT];
  int wid = tid >> 6, lane = tid & 63;
#pragma unroll
  for (int t = 0; t < TT; ++t) {
    float s = a0[t] + a1[t];
    float q = a0[t] * a0[t] + a1[t] * a1[t];
    s = wsum(s);
    q = wsum(q);
    if (lane == 0) { redS[wid][t] = s; redQ[wid][t] = q; }
  }
  __syncthreads();
  float2 g2 = *(const float2*)(cg + d0);
  float2 b2 = *(const float2*)(cb + d0);
#pragma unroll
  for (int t = 0; t < TT; ++t) {
    float s = redS[0][t] + redS[1][t] + redS[2][t] + redS[3][t];
    float q = redQ[0][t] + redQ[1][t] + redQ[2][t] + redQ[3][t];
    float mean = s * (1.0f / CD);
    float var = q * (1.0f / CD) - mean * mean;
    float rs = rsqrtf(var + 1e-5f);
    float y0 = (a0[t] - mean) * rs * g2.x + b2.x;
    float y1 = (a1[t] - mean) * rs * g2.y + b2.y;
    y0 = y0 * sigm(y0);
    y1 = y1 * sigm(y1);
    *(u32*)(out + ((long)(b * CT + t0 + t)) * CD + d0) = pack2(y0, y1);
  }
}

// ---------------------------------------------------------------------------
extern "C" void kernel_launch(void* const* d_in, const int* in_sizes, int n_in,
                              void* d_out, int out_size, void* d_ws, size_t ws_size,
                              hipStream_t stream) {
  const float* in_x   = (const float*)d_in[0];
  const float* in_pos = (const float*)d_in[1];
  const float* ln1_g  = (const float*)d_in[2];
  const float* ln1_b  = (const float*)d_in[3];
  const float* ff1_w1 = (const float*)d_in[4];
  const float* ff1_b1 = (const float*)d_in[5];
  const float* ff1_w2 = (const float*)d_in[6];
  const float* ff1_b2 = (const float*)d_in[7];
  const float* lnA_g  = (const float*)d_in[8];
  const float* lnA_b  = (const float*)d_in[9];
  const float* Wq     = (const float*)d_in[10];
  const float* bq     = (const float*)d_in[11];
  const float* Wk     = (const float*)d_in[12];
  const float* bk     = (const float*)d_in[13];
  const float* Wv     = (const float*)d_in[14];
  const float* bv     = (const float*)d_in[15];
  const float* Wo     = (const float*)d_in[16];
  const float* bo     = (const float*)d_in[17];
  const float* Wpos   = (const float*)d_in[18];
  const float* pbu    = (const float*)d_in[19];
  const float* pbv    = (const float*)d_in[20];
  const float* lnC_g  = (const float*)d_in[21];
  const float* lnC_b  = (const float*)d_in[22];
  const float* pw1_w  = (const float*)d_in[23];
  const float* pw1_b  = (const float*)d_in[24];
  const float* dw_w   = (const float*)d_in[25];
  const float* dw_b   = (const float*)d_in[26];
  const float* cln_g  = (const float*)d_in[27];
  const float* cln_b  = (const float*)d_in[28];
  const float* pw2_w  = (const float*)d_in[29];
  const float* pw2_b  = (const float*)d_in[30];
  const float* ln2_g  = (const float*)d_in[31];
  const float* ln2_b  = (const float*)d_in[32];
  const float* ff2_w1 = (const float*)d_in[33];
  const float* ff2_b1 = (const float*)d_in[34];
  const float* ff2_w2 = (const float*)d_in[35];
  const float* ff2_b2 = (const float*)d_in[36];
  const float* lnO_g  = (const float*)d_in[37];
  const float* lnO_b  = (const float*)d_in[38];
  (void)in_sizes; (void)n_in; (void)out_size; (void)ws_size;

  char* ws = (char*)d_ws;
  size_t off = 0;
  auto alloc = [&](size_t bytes) -> void* {
    off = (off + 255) & ~(size_t)255;
    void* p = ws + off;
    off += bytes;
    return p;
  };

  // weights (bf16, [N,K] layout)
  u16* wt_ff1w1 = (u16*)alloc((size_t)CL * CDFF * CD * 2);
  u16* wt_ff1w2 = (u16*)alloc((size_t)CL * CD * CDFF * 2);
  u16* wt_qkv   = (u16*)alloc((size_t)CL * 1536 * CD * 2);
  u16* wt_o     = (u16*)alloc((size_t)CL * CD * CD * 2);
  u16* wt_pos   = (u16*)alloc((size_t)CL * CD * CD * 2);
  u16* w_pw1    = (u16*)alloc((size_t)CL * 1024 * CD * 2);
  u16* w_pw2    = (u16*)alloc((size_t)CL * CD * CD * 2);
  u16* wt_ff2w1 = (u16*)alloc((size_t)CL * CDFF * CD * 2);
  u16* wt_ff2w2 = (u16*)alloc((size_t)CL * CD * CDFF * 2);
  float* qkvbias = (float*)alloc((size_t)CL * 1536 * 4);
  u16* posbf = (u16*)alloc((size_t)1024 * CD * 2);
  float* dwT = (float*)alloc((size_t)CL * 31 * CD * 4);
  // activations
  float* cur = (float*)alloc((size_t)CNBT * CD * 4);
  u16* ybf   = (u16*)alloc((size_t)CNBT * CD * 2);
  u16* qkv   = (u16*)alloc((size_t)CNBT * 1536 * 2);
  u16* hbf   = (u16*)alloc((size_t)CNBT * CDFF * 2);  // also pw1out f32 [4096,1024]
  u16* qu    = (u16*)alloc((size_t)CNBT * CD * 2);
  u16* qv    = (u16*)alloc((size_t)CNBT * CD * 2);
  u16* pbf   = (u16*)alloc((size_t)1024 * CD * 2);
  u16* vt    = (u16*)alloc((size_t)64 * CDK * CT * 2);
  float* S   = (float*)alloc((size_t)64 * CT * CT * 4);
  u16* probs = (u16*)alloc((size_t)64 * CT * CT * 2);
  u16* obf   = (u16*)alloc((size_t)CNBT * CD * 2);
  u16* ubuf  = (u16*)alloc((size_t)CNBT * CD * 2);
  u16* cbf   = (u16*)alloc((size_t)CNBT * CD * 2);

  dim3 b256(256);
  dim3 tb(32, 8);

  // ---- weight conversion (every call; deterministic) ----
  tconv_k<<<dim3(CDFF / 32, CD / 32, CL), tb, 0, stream>>>(ff1_w1, wt_ff1w1, CD, CDFF,
                                                           (long)CD * CDFF, (long)CDFF * CD);
  tconv_k<<<dim3(CD / 32, CDFF / 32, CL), tb, 0, stream>>>(ff1_w2, wt_ff1w2, CDFF, CD,
                                                           (long)CDFF * CD, (long)CD * CDFF);
  tconv_k<<<dim3(CD / 32, CD / 32, CL), tb, 0, stream>>>(Wq, wt_qkv, CD, CD,
                                                         (long)CD * CD, 1536L * CD);
  tconv_k<<<dim3(CD / 32, CD / 32, CL), tb, 0, stream>>>(Wk, wt_qkv + 512 * 512, CD, CD,
                                                         (long)CD * CD, 1536L * CD);
  tconv_k<<<dim3(CD / 32, CD / 32, CL), tb, 0, stream>>>(Wv, wt_qkv + 1024 * 512, CD, CD,
                                                         (long)CD * CD, 1536L * CD);
  tconv_k<<<dim3(CD / 32, CD / 32, CL), tb, 0, stream>>>(Wo, wt_o, CD, CD,
                                                         (long)CD * CD, (long)CD * CD);
  tconv_k<<<dim3(CD / 32, CD / 32, CL), tb, 0, stream>>>(Wpos, wt_pos, CD, CD,
                                                         (long)CD * CD, (long)CD * CD);
  tconv_k<<<dim3(CDFF / 32, CD / 32, CL), tb, 0, stream>>>(ff2_w1, wt_ff2w1, CD, CDFF,
                                                           (long)CD * CDFF, (long)CDFF * CD);
  tconv_k<<<dim3(CD / 32, CDFF / 32, CL), tb, 0, stream>>>(ff2_w2, wt_ff2w2, CDFF, CD,
                                                           (long)CDFF * CD, (long)CD * CDFF);
  cvt_k<<<dim3(512, CL, 1), b256, 0, stream>>>(pw1_w, w_pw1, 1024L * 512, 1024L * 512,
                                               1024L * 512, 1024L * 512);
  cvt_k<<<dim3(256, CL, 1), b256, 0, stream>>>(pw2_w, w_pw2, 512L * 512, 512L * 512,
                                               512L * 512, 512L * 512);
  cvt_k<<<dim3(512, 1, 1), b256, 0, stream>>>(in_pos, posbf, 1023L * 512, 1024L * 512, 0, 0);
  dwt_k<<<dim3(62, CL), b256, 0, stream>>>(dw_w, dwT);
  qkvbias_k<<<dim3(6, CL), b256, 0, stream>>>(bq, bk, bv, qkvbias);
  copy_k<<<dim3(2048), b256, 0, stream>>>(in_x, cur);

  for (int i = 0; i < CL; ++i) {
    const u16* Wf1 = wt_ff1w1 + (long)i * CDFF * CD;
    const u16* Wf2 = wt_ff1w2 + (long)i * CD * CDFF;
    const u16* Wqk = wt_qkv + (long)i * 1536 * CD;
    const u16* Wou = wt_o + (long)i * CD * CD;
    const u16* Wps = wt_pos + (long)i * CD * CD;
    const u16* Wp1 = w_pw1 + (long)i * 1024 * CD;
    const u16* Wp2 = w_pw2 + (long)i * CD * CD;
    const u16* Wf3 = wt_ff2w1 + (long)i * CDFF * CD;
    const u16* Wf4 = wt_ff2w2 + (long)i * CD * CDFF;

    // ---- FFN1 (half residual) ----
    ln_k<0><<<dim3(1024), b256, 0, stream>>>(cur, ybf, ln1_g + i * CD, ln1_b + i * CD);
    gemm_k<128, 128, 32, 64, 64, 2, false><<<dim3(32, 16, 1), b256, 0, stream>>>(
        ybf, Wf1, hbf, ff1_b1 + (long)i * CDFF, 0.f, CD, CD, CDFF, CD, 0, 0, 0, 0, 0, 0);
    gemm_k<128, 128, 32, 64, 64, 3, false><<<dim3(32, 4, 1), b256, 0, stream>>>(
        hbf, Wf2, cur, ff1_b2 + i * CD, 0.5f, CDFF, CDFF, CD, CDFF, 0, 0, 0, 0, 0, 0);

    // ---- rel-pos MHSA ----
    ln_k<0><<<dim3(1024), b256, 0, stream>>>(cur, ybf, lnA_g + i * CD, lnA_b + i * CD);
    gemm_k<128, 128, 32, 64, 64, 1, false><<<dim3(32, 12, 1), b256, 0, stream>>>(
        ybf, Wqk, qkv, qkvbias + i * 1536, 0.f, CD, CD, 1536, CD, 0, 0, 0, 0, 0, 0);
    gemm_k<128, 128, 32, 64, 64, 0, false><<<dim3(8, 4, 1), b256, 0, stream>>>(
        posbf, Wps, pbf, nullptr, 0.f, CD, CD, CD, CD, 0, 0, 0, 0, 0, 0);
    quqv_k<<<dim3(2048), b256, 0, stream>>>(qkv, pbu + i * 512, pbv + i * 512, qu, qv);
    vtrans_k<<<dim3(8, 64), b256, 0, stream>>>(qkv, vt);
    // AC: S[bh][t][s] = qu . k
    gemm_k<128, 128, 32, 64, 64, 5, true><<<dim3(4, 4, 64), b256, 0, stream>>>(
        qu, qkv + 512, S, nullptr, 0.f, 512, 1536, 512, 64,
        (long)CT * CD, 64, (long)CT * 1536, 64, (long)CH * CT * CT, (long)CT * CT);
    // BD: S[bh][t][j-511+t] += qv . p_j
    gemm_k<128, 128, 32, 64, 64, 6, true><<<dim3(4, 8, 64), b256, 0, stream>>>(
        qv, pbf, S, nullptr, 0.f, 512, 512, 512, 64,
        (long)CT * CD, 64, 0, 64, (long)CH * CT * CT, (long)CT * CT);
    softmax_k<<<dim3(8192), b256, 0, stream>>>(S, probs);
    // PV: o[b,t,h,d] = probs . vt
    gemm_k<128, 64, 32, 64, 32, 0, true><<<dim3(4, 1, 64), b256, 0, stream>>>(
        probs, vt, obf, nullptr, 0.f, 512, 512, 512, 512,
        (long)CH * CT * CT, (long)CT * CT, (long)CH * CDK * CT, (long)CDK * CT,
        (long)CT * CD, 64);
    gemm_k<128, 128, 32, 64, 64, 3, false><<<dim3(32, 4, 1), b256, 0, stream>>>(
        obf, Wou, cur, bo + i * CD, 1.0f, CD, CD, CD, CD, 0, 0, 0, 0, 0, 0);

    // ---- conv module ----
    ln_k<0><<<dim3(1024), b256, 0, stream>>>(cur, ybf, lnC_g + i * CD, lnC_b + i * CD);
    gemm_k<128, 128, 32, 64, 64, 4, false><<<dim3(32, 8, 1), b256, 0, stream>>>(
        ybf, Wp1, hbf, pw1_b + (long)i * 1024, 0.f, CD, CD, 1024, CD, 0, 0, 0, 0, 0, 0);
    glu_k<<<dim3(2048), b256, 0, stream>>>((const float*)hbf, ubuf);
    conv2_k<<<dim3(CT / 8, 8), b256, 0, stream>>>(ubuf, dwT + (long)i * 31 * CD,
                                                  dw_b + i * CD, cln_g + i * CD,
                                                  cln_b + i * CD, cbf);
    gemm_k<128, 128, 32, 64, 64, 3, false><<<dim3(32, 4, 1), b256, 0, stream>>>(
        cbf, Wp2, cur, pw2_b + i * CD, 1.0f, CD, CD, CD, CD, 0, 0, 0, 0, 0, 0);

    // ---- FFN2 (half residual) ----
    ln_k<0><<<dim3(1024), b256, 0, stream>>>(cur, ybf, ln2_g + i * CD, ln2_b + i * CD);
    gemm_k<128, 128, 32, 64, 64, 2, false><<<dim3(32, 16, 1), b256, 0, stream>>>(
        ybf, Wf3, hbf, ff2_b1 + (long)i * CDFF, 0.f, CD, CD, CDFF, CD, 0, 0, 0, 0, 0, 0);
    gemm_k<128, 128, 32, 64, 64, 3, false><<<dim3(32, 4, 1), b256, 0, stream>>>(
        hbf, Wf4, cur, ff2_b2 + i * CD, 0.5f, CDFF, CDFF, CD, CDFF, 0, 0, 0, 0, 0, 0);

    // ---- output LN ----
    if (i < CL - 1)
      ln_k<1><<<dim3(1024), b256, 0, stream>>>(cur, cur, lnO_g + i * CD, lnO_b + i * CD);
    else
      ln_k<1><<<dim3(1024), b256, 0, stream>>>(cur, d_out, lnO_g + i * CD, lnO_b + i * CD);
  }
}

// Round 3
// 1508.091 us; speedup vs baseline: 1.6500x; 1.1638x over previous
//
#include <hip/hip_runtime.h>

// ---------------------------------------------------------------------------
// Conformer encoder, MI355X bf16-MFMA implementation.
// Round 2: fused rel-pos flash attention (AC + shifted-BD + online softmax +
// PV in one kernel) replaces the fp32 score materialization path that was
// ~600us of memory-bound GEMMs.
// ---------------------------------------------------------------------------

typedef unsigned short u16;
typedef unsigned int u32;
typedef __attribute__((ext_vector_type(8))) short bf16x8;
typedef __attribute__((ext_vector_type(4))) float f32x4;

#define DI __device__ __forceinline__

constexpr int CT = 512;     // sequence length T
constexpr int CD = 512;     // model dim D
constexpr int CH = 8;       // heads
constexpr int CDK = 64;     // head dim
constexpr int CDFF = 2048;  // ffn dim
constexpr int CNBT = 4096;  // B*T
constexpr int CL = 4;       // layers

DI u16 f2bf(float f) {
  u32 u = __builtin_bit_cast(u32, f);
  u = u + 0x7fffu + ((u >> 16) & 1u);
  return (u16)(u >> 16);
}
DI float bf2f(u16 h) { u32 u = ((u32)h) << 16; return __builtin_bit_cast(float, u); }
DI u32 pack2(float a, float b) { return (u32)f2bf(a) | ((u32)f2bf(b) << 16); }
DI float sigm(float x) { return 1.0f / (1.0f + __expf(-x)); }

DI f32x4 MFMA(bf16x8 a, bf16x8 b, f32x4 c) {
  return __builtin_amdgcn_mfma_f32_16x16x32_bf16(a, b, c, 0, 0, 0);
}

DI void gload16(const void* g, void* l) {
  __builtin_amdgcn_global_load_lds((const __attribute__((address_space(1))) void*)g,
                                   (__attribute__((address_space(3))) void*)l, 16, 0, 0);
}

DI float wsum(float v) {
#pragma unroll
  for (int o = 32; o > 0; o >>= 1) v += __shfl_xor(v, o, 64);
  return v;
}

// ------------------------- weight conversion -------------------------------
// fp32 [R,C] -> bf16 [C,R]  (per-z slice, separate in/out z strides)
__global__ __launch_bounds__(256) void tconv_k(const float* __restrict__ in,
                                               u16* __restrict__ out, int R, int C,
                                               long inZ, long outZ) {
  __shared__ float t[32][33];
  int c0 = blockIdx.x * 32, r0 = blockIdx.y * 32;
  const float* ip = in + (long)blockIdx.z * inZ;
  u16* op = out + (long)blockIdx.z * outZ;
#pragma unroll
  for (int i = threadIdx.y; i < 32; i += 8)
    t[i][threadIdx.x] = ip[(long)(r0 + i) * C + c0 + threadIdx.x];
  __syncthreads();
#pragma unroll
  for (int i = threadIdx.y; i < 32; i += 8)
    op[(long)(c0 + i) * R + r0 + threadIdx.x] = f2bf(t[threadIdx.x][i]);
}

// fp32 -> bf16 flat, zero-fill beyond nIn (used to pad pos_emb to 1024 rows)
__global__ __launch_bounds__(256) void cvt_k(const float* __restrict__ in,
                                             u16* __restrict__ out, long nIn, long nOut,
                                             long inZ, long outZ) {
  long i = ((long)blockIdx.x * 256 + threadIdx.x) * 4;
  if (i >= nOut) return;
  const float* ip = in + (long)blockIdx.y * inZ;
  u16* op = out + (long)blockIdx.y * outZ;
  u16 o[4];
#pragma unroll
  for (int j = 0; j < 4; ++j) {
    long idx = i + j;
    o[j] = (idx < nIn) ? f2bf(ip[idx]) : (u16)0;
  }
  uint2 st;
  st.x = (u32)o[0] | ((u32)o[1] << 16);
  st.y = (u32)o[2] | ((u32)o[3] << 16);
  *(uint2*)&op[i] = st;
}

// dw_w [L][512][31] -> wT [L][31][512] fp32
__global__ __launch_bounds__(256) void dwt_k(const float* __restrict__ in,
                                             float* __restrict__ out) {
  int l = blockIdx.y;
  int idx = blockIdx.x * 256 + threadIdx.x;
  if (idx >= 512 * 31) return;
  int k = idx >> 9, d = idx & 511;
  out[(long)l * 31 * 512 + idx] = in[(long)l * 512 * 31 + d * 31 + k];
}

__global__ __launch_bounds__(256) void qkvbias_k(const float* __restrict__ bq,
                                                 const float* __restrict__ bk,
                                                 const float* __restrict__ bv,
                                                 float* __restrict__ out) {
  int z = blockIdx.y;
  int j = blockIdx.x * 256 + threadIdx.x;
  float v;
  if (j < 512) v = bq[z * 512 + j];
  else if (j < 1024) v = bk[z * 512 + j - 512];
  else v = bv[z * 512 + j - 1024];
  out[z * 1536 + j] = v;
}

__global__ __launch_bounds__(256) void copy_k(const float* __restrict__ in,
                                              float* __restrict__ out) {
  long i = ((long)blockIdx.x * 256 + threadIdx.x) * 4;
  *(float4*)(out + i) = *(const float4*)(in + i);
}

// ------------------------------- LayerNorm ---------------------------------
// one wave per row of 512; F32OUT=0 -> bf16 out, 1 -> fp32 out (in==out ok)
template <int F32OUT>
__global__ __launch_bounds__(256) void ln_k(const float* in, void* out,
                                            const float* gw, const float* bw) {
  int tid = threadIdx.x, wid = tid >> 6, lane = tid & 63;
  long row = (long)blockIdx.x * 4 + wid;
  const float* x = in + row * CD + lane * 8;
  float4 v0 = *(const float4*)x;
  float4 v1 = *(const float4*)(x + 4);
  float s = v0.x + v0.y + v0.z + v0.w + v1.x + v1.y + v1.z + v1.w;
  float q = v0.x * v0.x + v0.y * v0.y + v0.z * v0.z + v0.w * v0.w +
            v1.x * v1.x + v1.y * v1.y + v1.z * v1.z + v1.w * v1.w;
  s = wsum(s);
  q = wsum(q);
  float mean = s * (1.0f / CD);
  float var = q * (1.0f / CD) - mean * mean;
  float rs = rsqrtf(var + 1e-5f);
  int c = lane * 8;
  float4 g0 = *(const float4*)(gw + c), g1 = *(const float4*)(gw + c + 4);
  float4 b0 = *(const float4*)(bw + c), b1 = *(const float4*)(bw + c + 4);
  float y0 = (v0.x - mean) * rs * g0.x + b0.x;
  float y1 = (v0.y - mean) * rs * g0.y + b0.y;
  float y2 = (v0.z - mean) * rs * g0.z + b0.z;
  float y3 = (v0.w - mean) * rs * g0.w + b0.w;
  float y4 = (v1.x - mean) * rs * g1.x + b1.x;
  float y5 = (v1.y - mean) * rs * g1.y + b1.y;
  float y6 = (v1.z - mean) * rs * g1.z + b1.z;
  float y7 = (v1.w - mean) * rs * g1.w + b1.w;
  if (F32OUT) {
    float* o = (float*)out + row * CD + c;
    *(float4*)o = make_float4(y0, y1, y2, y3);
    *(float4*)(o + 4) = make_float4(y4, y5, y6, y7);
  } else {
    u16* o = (u16*)out + row * CD + c;
    uint4 pk;
    pk.x = pack2(y0, y1);
    pk.y = pack2(y2, y3);
    pk.z = pack2(y4, y5);
    pk.w = pack2(y6, y7);
    *(uint4*)o = pk;
  }
}

// --------------------------------- GEMM ------------------------------------
// C[m,n] = sum_k A[m,k] * B[n,k]   (A row-major [M,K], B row-major [N,K])
// EPI: 0 store bf16 | 1 +bias bf16 | 2 +bias swish bf16 | 3 res += alpha*(v+bias)
//      4 +bias f32
template <int BM, int BN, int BK, int WM, int WN, int EPI>
__global__ __launch_bounds__(256) void gemm_k(
    const u16* __restrict__ A, const u16* __restrict__ B, void* C,
    const float* __restrict__ bias, float alpha, int lda, int ldb, int ldc, int Kd) {
  static_assert(BK == 32, "");
  static_assert((BM / WM) * (BN / WN) == 4, "");
  __shared__ u16 ldsA[BM * BK];
  __shared__ u16 ldsB[BN * BK];
  const int tid = threadIdx.x, wid = tid >> 6, lane = tid & 63;
  const int m0 = blockIdx.x * BM, n0 = blockIdx.y * BN;
  constexpr int nWn = BN / WN;
  const int wm = wid / nWn, wn = wid % nWn;
  constexpr int FM = WM / 16, FN = WN / 16;
  const f32x4 vzero = {0.f, 0.f, 0.f, 0.f};
  f32x4 acc[FM][FN];
#pragma unroll
  for (int mi = 0; mi < FM; ++mi)
#pragma unroll
    for (int ni = 0; ni < FN; ++ni) acc[mi][ni] = vzero;

  const int ar = lane & 15, kq = (lane >> 4) * 8;
  constexpr int AR = (BM * BK * 2) / 4096;
  constexpr int BR = (BN * BK * 2) / 4096;

  for (int k0 = 0; k0 < Kd; k0 += BK) {
    __syncthreads();
#pragma unroll
    for (int r = 0; r < AR; ++r) {
      int boff = r * 4096 + tid * 16;
      int row = boff >> 6;           // 64 B per 32-elem bf16 row
      int ke = (boff & 63) >> 1;
      gload16(A + (long)(m0 + row) * lda + k0 + ke,
              (char*)ldsA + r * 4096 + wid * 1024);
    }
#pragma unroll
    for (int r = 0; r < BR; ++r) {
      int boff = r * 4096 + tid * 16;
      int row = boff >> 6;
      int ke = (boff & 63) >> 1;
      gload16(B + (long)(n0 + row) * ldb + k0 + ke,
              (char*)ldsB + r * 4096 + wid * 1024);
    }
    asm volatile("s_waitcnt vmcnt(0)" ::: "memory");
    __syncthreads();
    bf16x8 af[FM], bfr[FN];
#pragma unroll
    for (int mi = 0; mi < FM; ++mi)
      af[mi] = *(const bf16x8*)&ldsA[(wm * WM + mi * 16 + ar) * BK + kq];
#pragma unroll
    for (int ni = 0; ni < FN; ++ni)
      bfr[ni] = *(const bf16x8*)&ldsB[(wn * WN + ni * 16 + ar) * BK + kq];
#pragma unroll
    for (int mi = 0; mi < FM; ++mi)
#pragma unroll
      for (int ni = 0; ni < FN; ++ni)
        acc[mi][ni] = MFMA(af[mi], bfr[ni], acc[mi][ni]);
  }

#pragma unroll
  for (int mi = 0; mi < FM; ++mi) {
    const int gmB = m0 + wm * WM + mi * 16 + (lane >> 4) * 4;
#pragma unroll
    for (int ni = 0; ni < FN; ++ni) {
      const int gn = n0 + wn * WN + ni * 16 + (lane & 15);
      float bv_ = 0.f;
      if constexpr (EPI == 1 || EPI == 2 || EPI == 3 || EPI == 4) bv_ = bias[gn];
#pragma unroll
      for (int r = 0; r < 4; ++r) {
        const int gm = gmB + r;
        float v = acc[mi][ni][r];
        long idx = (long)gm * ldc + gn;
        if constexpr (EPI == 0) ((u16*)C)[idx] = f2bf(v);
        else if constexpr (EPI == 1) ((u16*)C)[idx] = f2bf(v + bv_);
        else if constexpr (EPI == 2) {
          float x = v + bv_;
          ((u16*)C)[idx] = f2bf(x * sigm(x));
        } else if constexpr (EPI == 3) {
          float* R = (float*)C;
          R[idx] += alpha * (v + bv_);
        } else if constexpr (EPI == 4) ((float*)C)[idx] = v + bv_;
      }
    }
  }
}

// ---------------------------- attention helpers ----------------------------
// qu = q + pbu, qv = q + pbv  (q = first 512 cols of qkv)
__global__ __launch_bounds__(256) void quqv_k(const u16* __restrict__ qkv,
                                              const float* __restrict__ pbu,
                                              const float* __restrict__ pbv,
                                              u16* __restrict__ qu, u16* __restrict__ qv) {
  long i = (long)blockIdx.x * 256 + threadIdx.x;  // 4 elems each
  long r = i >> 7;
  int c = (int)(i & 127) * 4;
  const u16* q = qkv + r * 1536 + c;
  uint2 qq = *(const uint2*)q;
  float f0 = bf2f((u16)(qq.x & 0xffff)), f1 = bf2f((u16)(qq.x >> 16));
  float f2 = bf2f((u16)(qq.y & 0xffff)), f3 = bf2f((u16)(qq.y >> 16));
  float4 bu = *(const float4*)(pbu + c);
  float4 bv = *(const float4*)(pbv + c);
  uint2 ou, ov;
  ou.x = pack2(f0 + bu.x, f1 + bu.y);
  ou.y = pack2(f2 + bu.z, f3 + bu.w);
  ov.x = pack2(f0 + bv.x, f1 + bv.y);
  ov.y = pack2(f2 + bv.z, f3 + bv.w);
  *(uint2*)&qu[r * 512 + c] = ou;
  *(uint2*)&qv[r * 512 + c] = ov;
}

// vt[bh][d][t] = v[b,t,h,d]  (v = cols 1024..1535 of qkv)
__global__ __launch_bounds__(256) void vtrans_k(const u16* __restrict__ qkv,
                                                u16* __restrict__ vt) {
  __shared__ u16 t[64][80];
  int tid = threadIdx.x;
  int t0 = blockIdx.x * 64;
  int bh = blockIdx.y, b = bh >> 3, h = bh & 7;
  {
    int tl = tid >> 2, dg = (tid & 3) * 16;
    const u16* src = qkv + ((long)(b * CT + t0 + tl)) * 1536 + 1024 + h * 64 + dg;
    uint4 a0 = *(const uint4*)src;
    uint4 a1 = *(const uint4*)(src + 8);
    *(uint4*)&t[tl][dg] = a0;
    *(uint4*)&t[tl][dg + 8] = a1;
  }
  __syncthreads();
  {
    int dl = tid >> 2, tg = (tid & 3) * 16;
    u16* dst = vt + ((long)bh * 64 + dl) * CT + t0 + tg;
    u16 tmp[16];
#pragma unroll
    for (int j = 0; j < 16; ++j) tmp[j] = t[tg + j][dl];
    uint4 o0, o1;
    o0.x = (u32)tmp[0] | ((u32)tmp[1] << 16);
    o0.y = (u32)tmp[2] | ((u32)tmp[3] << 16);
    o0.z = (u32)tmp[4] | ((u32)tmp[5] << 16);
    o0.w = (u32)tmp[6] | ((u32)tmp[7] << 16);
    o1.x = (u32)tmp[8] | ((u32)tmp[9] << 16);
    o1.y = (u32)tmp[10] | ((u32)tmp[11] << 16);
    o1.z = (u32)tmp[12] | ((u32)tmp[13] << 16);
    o1.w = (u32)tmp[14] | ((u32)tmp[15] << 16);
    *(uint4*)dst = o0;
    *(uint4*)(dst + 8) = o1;
  }
}

// ---------------- fused rel-pos flash attention ----------------------------
// block: (t-tile 64 of one (b,h)); 4 waves in 2x2 (t x s/d) arrangement.
// Loops s-tiles of 128: AC via MFMA, bd0 = qv*p via MFMA -> LDS, shift-read,
// online softmax (P bf16 in LDS), PV accumulate; writes o [b,t,h,d].
__global__ __launch_bounds__(256, 2) void attn_k(
    const u16* __restrict__ qu, const u16* __restrict__ qv,
    const u16* __restrict__ qkvp, const u16* __restrict__ pbf,
    const u16* __restrict__ vt, u16* __restrict__ out) {
  __shared__ u16 bd0s[64 * 192];     // [t][jrel], XOR-swizzled
  __shared__ u16 stile[64 * 128];    // scores then P, XOR-swizzled
  __shared__ float rowscale[64];
  __shared__ float rowlinv[64];
  const int tid = threadIdx.x, wid = tid >> 6, lane = tid & 63;
  const int t0 = blockIdx.x * 64;
  const int bh = blockIdx.y, b = bh >> 3, h = bh & 7;
  const int wt = wid >> 1, ws = wid & 1;
  const int fr = lane & 15, fq = lane >> 4;
  const int srow = wid * 16 + (lane >> 2);  // stats row, 4 lanes per row
  const int qrt = lane & 3;

  const f32x4 vz = {0.f, 0.f, 0.f, 0.f};
  f32x4 oacc[2][2] = {{vz, vz}, {vz, vz}};
  float m_run = -1e30f, l_run = 0.f;

  const long qrowA = (long)(b * CT + t0 + wt * 32) * CD + h * CDK;
  const u16* kbase = qkvp + (long)(b * CT) * 1536 + 512 + h * CDK;

  for (int st = 0; st < 4; ++st) {
    const int s0 = st * 128;
    __syncthreads();  // previous iteration's PV reads done
    // ---- AC = qu . k ----
    f32x4 ac[2][4] = {{vz, vz, vz, vz}, {vz, vz, vz, vz}};
#pragma unroll
    for (int kk = 0; kk < 2; ++kk) {
      const int ko = kk * 32 + fq * 8;
      bf16x8 a0 = *(const bf16x8*)&qu[qrowA + (long)(fr)*CD + ko];
      bf16x8 a1 = *(const bf16x8*)&qu[qrowA + (long)(16 + fr) * CD + ko];
#pragma unroll
      for (int ni = 0; ni < 4; ++ni) {
        bf16x8 bb = *(const bf16x8*)&kbase[(long)(s0 + ws * 64 + ni * 16 + fr) * 1536 + ko];
        ac[0][ni] = MFMA(a0, bb, ac[0][ni]);
        ac[1][ni] = MFMA(a1, bb, ac[1][ni]);
      }
    }
    // ---- bd0 = qv . p  (un-shifted, 192 jrel cols) ----
    const int j0 = s0 - t0 + 448;
    f32x4 bd[2][6] = {{vz, vz, vz, vz, vz, vz}, {vz, vz, vz, vz, vz, vz}};
#pragma unroll
    for (int kk = 0; kk < 2; ++kk) {
      const int ko = kk * 32 + fq * 8;
      bf16x8 a0 = *(const bf16x8*)&qv[qrowA + (long)(fr)*CD + ko];
      bf16x8 a1 = *(const bf16x8*)&qv[qrowA + (long)(16 + fr) * CD + ko];
#pragma unroll
      for (int ni = 0; ni < 6; ++ni) {
        bf16x8 bb = *(const bf16x8*)&pbf[(long)(j0 + ws * 96 + ni * 16 + fr) * CD + h * CDK + ko];
        bd[0][ni] = MFMA(a0, bb, bd[0][ni]);
        bd[1][ni] = MFMA(a1, bb, bd[1][ni]);
      }
    }
#pragma unroll
    for (int mi = 0; mi < 2; ++mi)
#pragma unroll
      for (int ni = 0; ni < 6; ++ni)
#pragma unroll
        for (int r = 0; r < 4; ++r) {
          int tl = wt * 32 + mi * 16 + fq * 4 + r;
          int jl = ws * 96 + ni * 16 + fr;
          *(u16*)((char*)bd0s + ((tl * 384 + jl * 2) ^ ((tl & 7) << 4))) = f2bf(bd[mi][ni][r]);
        }
    __syncthreads();
    // ---- combine: score = 0.125*(ac + bd0[t][s+63-t]) -> stile bf16 ----
#pragma unroll
    for (int mi = 0; mi < 2; ++mi)
#pragma unroll
      for (int ni = 0; ni < 4; ++ni)
#pragma unroll
        for (int r = 0; r < 4; ++r) {
          int tl = wt * 32 + mi * 16 + fq * 4 + r;
          int sl = ws * 64 + ni * 16 + fr;
          int jl = sl + 63 - tl;
          u16 bv16 = *(const u16*)((const char*)bd0s + ((tl * 384 + jl * 2) ^ ((tl & 7) << 4)));
          float sc = (ac[mi][ni][r] + bf2f(bv16)) * 0.125f;
          *(u16*)((char*)stile + ((tl * 256 + sl * 2) ^ ((tl & 7) << 4))) = f2bf(sc);
        }
    __syncthreads();
    // ---- online softmax stats (4 lanes per row, 32 cols each) ----
    {
      const int swz = (srow & 7) << 4;
      const int rb = srow * 256 + qrt * 64;
      float vals[32];
#pragma unroll
      for (int c = 0; c < 4; ++c) {
        bf16x8 v8 = *(const bf16x8*)((const char*)stile + ((rb + c * 16) ^ swz));
#pragma unroll
        for (int j = 0; j < 8; ++j) vals[c * 8 + j] = bf2f((u16)v8[j]);
      }
      float mx = vals[0];
#pragma unroll
      for (int j = 1; j < 32; ++j) mx = fmaxf(mx, vals[j]);
      mx = fmaxf(mx, __shfl_xor(mx, 1));
      mx = fmaxf(mx, __shfl_xor(mx, 2));
      float mnew = fmaxf(m_run, mx);
      float sum = 0.f;
#pragma unroll
      for (int j = 0; j < 32; ++j) {
        float p = __expf(vals[j] - mnew);
        vals[j] = p;
        sum += p;
      }
      sum += __shfl_xor(sum, 1);
      sum += __shfl_xor(sum, 2);
      float scf = __expf(m_run - mnew);
      l_run = l_run * scf + sum;
      m_run = mnew;
#pragma unroll
      for (int c = 0; c < 4; ++c) {
        uint4 pk;
        pk.x = pack2(vals[c * 8 + 0], vals[c * 8 + 1]);
        pk.y = pack2(vals[c * 8 + 2], vals[c * 8 + 3]);
        pk.z = pack2(vals[c * 8 + 4], vals[c * 8 + 5]);
        pk.w = pack2(vals[c * 8 + 6], vals[c * 8 + 7]);
        *(uint4*)((char*)stile + ((rb + c * 16) ^ swz)) = pk;
      }
      if (qrt == 0) rowscale[srow] = scf;
    }
    __syncthreads();
    // ---- rescale o-acc, PV accumulate ----
#pragma unroll
    for (int mi = 0; mi < 2; ++mi)
#pragma unroll
      for (int r = 0; r < 4; ++r) {
        float s = rowscale[wt * 32 + mi * 16 + fq * 4 + r];
        oacc[mi][0][r] *= s;
        oacc[mi][1][r] *= s;
      }
#pragma unroll
    for (int kk = 0; kk < 4; ++kk) {
      bf16x8 pa[2];
#pragma unroll
      for (int mi = 0; mi < 2; ++mi) {
        int tl = wt * 32 + mi * 16 + fr;
        pa[mi] = *(const bf16x8*)((const char*)stile +
                                  ((tl * 256 + kk * 64 + fq * 16) ^ ((tl & 7) << 4)));
      }
#pragma unroll
      for (int ni = 0; ni < 2; ++ni) {
        bf16x8 vb = *(const bf16x8*)&vt[((long)bh * 64 + ws * 32 + ni * 16 + fr) * 512 +
                                        s0 + kk * 32 + fq * 8];
        oacc[0][ni] = MFMA(pa[0], vb, oacc[0][ni]);
        oacc[1][ni] = MFMA(pa[1], vb, oacc[1][ni]);
      }
    }
  }
  if (qrt == 0) rowlinv[srow] = 1.0f / l_run;
  __syncthreads();
#pragma unroll
  for (int mi = 0; mi < 2; ++mi)
#pragma unroll
    for (int r = 0; r < 4; ++r) {
      int tl = wt * 32 + mi * 16 + fq * 4 + r;
      float inv = rowlinv[tl];
      long row = (long)(b * CT + t0 + tl) * CD + h * CDK + ws * 32;
#pragma unroll
      for (int ni = 0; ni < 2; ++ni)
        out[row + ni * 16 + fr] = f2bf(oacc[mi][ni][r] * inv);
    }
}

// ------------------------------ conv module --------------------------------
__global__ __launch_bounds__(256) void glu_k(const float* __restrict__ p,
                                             u16* __restrict__ u) {
  long i = (long)blockIdx.x * 256 + threadIdx.x;  // 4 elems each
  long r = i >> 7;
  int c = (int)(i & 127) * 4;
  const float* pr = p + r * 1024;
  float4 a = *(const float4*)(pr + c);
  float4 g = *(const float4*)(pr + 512 + c);
  uint2 o;
  o.x = pack2(a.x * sigm(g.x), a.y * sigm(g.y));
  o.y = pack2(a.z * sigm(g.z), a.w * sigm(g.w));
  *(uint2*)&u[r * 512 + c] = o;
}

// depthwise conv(K=31,pad 15) + dw_b + LN(cln) + swish.
// block = (t-tile of 8, b); thread owns channels (2*tid, 2*tid+1) x 8 t's.
__global__ __launch_bounds__(256) void conv2_k(const u16* __restrict__ u,
                                               const float* __restrict__ wT,
                                               const float* __restrict__ wb,
                                               const float* __restrict__ cg,
                                               const float* __restrict__ cb,
                                               u16* __restrict__ out) {
  constexpr int TT = 8;
  int tid = threadIdx.x, d0 = tid * 2;
  int b = blockIdx.y, t0 = blockIdx.x * TT;
  const u16* ub = u + ((long)b * CT) * CD + d0;

  u32 strip[TT + 30];
#pragma unroll
  for (int j = 0; j < TT + 30; ++j) {
    int tt = t0 + j - 15;
    strip[j] = ((unsigned)tt < (unsigned)CT) ? *(const u32*)(ub + (long)tt * CD) : 0u;
  }
  float2 bias = *(const float2*)(wb + d0);
  float a0[TT], a1[TT];
#pragma unroll
  for (int t = 0; t < TT; ++t) { a0[t] = bias.x; a1[t] = bias.y; }
#pragma unroll
  for (int k = 0; k < 31; ++k) {
    float2 wk = *(const float2*)(wT + k * CD + d0);
#pragma unroll
    for (int t = 0; t < TT; ++t) {
      u32 pr = strip[t + k];
      a0[t] += bf2f((u16)(pr & 0xffff)) * wk.x;
      a1[t] += bf2f((u16)(pr >> 16)) * wk.y;
    }
  }
  __shared__ float redS[4][TT], redQ[4][TT];
  int wid = tid >> 6, lane = tid & 63;
#pragma unroll
  for (int t = 0; t < TT; ++t) {
    float s = a0[t] + a1[t];
    float q = a0[t] * a0[t] + a1[t] * a1[t];
    s = wsum(s);
    q = wsum(q);
    if (lane == 0) { redS[wid][t] = s; redQ[wid][t] = q; }
  }
  __syncthreads();
  float2 g2 = *(const float2*)(cg + d0);
  float2 b2 = *(const float2*)(cb + d0);
#pragma unroll
  for (int t = 0; t < TT; ++t) {
    float s = redS[0][t] + redS[1][t] + redS[2][t] + redS[3][t];
    float q = redQ[0][t] + redQ[1][t] + redQ[2][t] + redQ[3][t];
    float mean = s * (1.f / 512), var = q * (1.f / 512) - mean * mean;
    float rs = rsqrtf(var + 1e-5f);
    float y0 = (a0[t] - mean) * rs * g2.x + b2.x;
    float y1 = (a1[t] - mean) * rs * g2.y + b2.y;
    y0 = y0 * sigm(y0);
    y1 = y1 * sigm(y1);
    *(u32*)(out + ((long)(b * CT + t0 + t)) * CD + d0) = pack2(y0, y1);
  }
}

// ---------------------------------------------------------------------------
extern "C" void kernel_launch(void* const* d_in, const int* in_sizes, int n_in,
                              void* d_out, int out_size, void* d_ws, size_t ws_size,
                              hipStream_t stream) {
  const float* in_x   = (const float*)d_in[0];
  const float* in_pos = (const float*)d_in[1];
  const float* ln1_g  = (const float*)d_in[2];
  const float* ln1_b  = (const float*)d_in[3];
  const float* ff1_w1 = (const float*)d_in[4];
  const float* ff1_b1 = (const float*)d_in[5];
  const float* ff1_w2 = (const float*)d_in[6];
  const float* ff1_b2 = (const float*)d_in[7];
  const float* lnA_g  = (const float*)d_in[8];
  const float* lnA_b  = (const float*)d_in[9];
  const float* Wq     = (const float*)d_in[10];
  const float* bq     = (const float*)d_in[11];
  const float* Wk     = (const float*)d_in[12];
  const float* bk     = (const float*)d_in[13];
  const float* Wv     = (const float*)d_in[14];
  const float* bv     = (const float*)d_in[15];
  const float* Wo     = (const float*)d_in[16];
  const float* bo     = (const float*)d_in[17];
  const float* Wpos   = (const float*)d_in[18];
  const float* pbu    = (const float*)d_in[19];
  const float* pbv    = (const float*)d_in[20];
  const float* lnC_g  = (const float*)d_in[21];
  const float* lnC_b  = (const float*)d_in[22];
  const float* pw1_w  = (const float*)d_in[23];
  const float* pw1_b  = (const float*)d_in[24];
  const float* dw_w   = (const float*)d_in[25];
  const float* dw_b   = (const float*)d_in[26];
  const float* cln_g  = (const float*)d_in[27];
  const float* cln_b  = (const float*)d_in[28];
  const float* pw2_w  = (const float*)d_in[29];
  const float* pw2_b  = (const float*)d_in[30];
  const float* ln2_g  = (const float*)d_in[31];
  const float* ln2_b  = (const float*)d_in[32];
  const float* ff2_w1 = (const float*)d_in[33];
  const float* ff2_b1 = (const float*)d_in[34];
  const float* ff2_w2 = (const float*)d_in[35];
  const float* ff2_b2 = (const float*)d_in[36];
  const float* lnO_g  = (const float*)d_in[37];
  const float* lnO_b  = (const float*)d_in[38];
  (void)in_sizes; (void)n_in; (void)out_size; (void)ws_size;

  char* ws = (char*)d_ws;
  size_t off = 0;
  auto alloc = [&](size_t bytes) -> void* {
    off = (off + 255) & ~(size_t)255;
    void* p = ws + off;
    off += bytes;
    return p;
  };

  // weights (bf16, [N,K] layout)
  u16* wt_ff1w1 = (u16*)alloc((size_t)CL * CDFF * CD * 2);
  u16* wt_ff1w2 = (u16*)alloc((size_t)CL * CD * CDFF * 2);
  u16* wt_qkv   = (u16*)alloc((size_t)CL * 1536 * CD * 2);
  u16* wt_o     = (u16*)alloc((size_t)CL * CD * CD * 2);
  u16* wt_pos   = (u16*)alloc((size_t)CL * CD * CD * 2);
  u16* w_pw1    = (u16*)alloc((size_t)CL * 1024 * CD * 2);
  u16* w_pw2    = (u16*)alloc((size_t)CL * CD * CD * 2);
  u16* wt_ff2w1 = (u16*)alloc((size_t)CL * CDFF * CD * 2);
  u16* wt_ff2w2 = (u16*)alloc((size_t)CL * CD * CDFF * 2);
  float* qkvbias = (float*)alloc((size_t)CL * 1536 * 4);
  u16* posbf = (u16*)alloc((size_t)1024 * CD * 2);
  float* dwT = (float*)alloc((size_t)CL * 31 * CD * 4);
  // activations
  float* cur = (float*)alloc((size_t)CNBT * CD * 4);
  u16* ybf   = (u16*)alloc((size_t)CNBT * CD * 2);
  u16* qkv   = (u16*)alloc((size_t)CNBT * 1536 * 2);
  u16* hbf   = (u16*)alloc((size_t)CNBT * CDFF * 2);  // also pw1out f32 [4096,1024]
  u16* qu    = (u16*)alloc((size_t)CNBT * CD * 2);
  u16* qv    = (u16*)alloc((size_t)CNBT * CD * 2);
  u16* pbf   = (u16*)alloc((size_t)1024 * CD * 2);
  u16* vt    = (u16*)alloc((size_t)64 * CDK * CT * 2);
  u16* obf   = (u16*)alloc((size_t)CNBT * CD * 2);
  u16* ubuf  = (u16*)alloc((size_t)CNBT * CD * 2);
  u16* cbf   = (u16*)alloc((size_t)CNBT * CD * 2);

  dim3 b256(256);
  dim3 tb(32, 8);

  // ---- weight conversion (every call; deterministic) ----
  tconv_k<<<dim3(CDFF / 32, CD / 32, CL), tb, 0, stream>>>(ff1_w1, wt_ff1w1, CD, CDFF,
                                                           (long)CD * CDFF, (long)CDFF * CD);
  tconv_k<<<dim3(CD / 32, CDFF / 32, CL), tb, 0, stream>>>(ff1_w2, wt_ff1w2, CDFF, CD,
                                                           (long)CDFF * CD, (long)CD * CDFF);
  tconv_k<<<dim3(CD / 32, CD / 32, CL), tb, 0, stream>>>(Wq, wt_qkv, CD, CD,
                                                         (long)CD * CD, 1536L * CD);
  tconv_k<<<dim3(CD / 32, CD / 32, CL), tb, 0, stream>>>(Wk, wt_qkv + 512 * 512, CD, CD,
                                                         (long)CD * CD, 1536L * CD);
  tconv_k<<<dim3(CD / 32, CD / 32, CL), tb, 0, stream>>>(Wv, wt_qkv + 1024 * 512, CD, CD,
                                                         (long)CD * CD, 1536L * CD);
  tconv_k<<<dim3(CD / 32, CD / 32, CL), tb, 0, stream>>>(Wo, wt_o, CD, CD,
                                                         (long)CD * CD, (long)CD * CD);
  tconv_k<<<dim3(CD / 32, CD / 32, CL), tb, 0, stream>>>(Wpos, wt_pos, CD, CD,
                                                         (long)CD * CD, (long)CD * CD);
  tconv_k<<<dim3(CDFF / 32, CD / 32, CL), tb, 0, stream>>>(ff2_w1, wt_ff2w1, CD, CDFF,
                                                           (long)CD * CDFF, (long)CDFF * CD);
  tconv_k<<<dim3(CD / 32, CDFF / 32, CL), tb, 0, stream>>>(ff2_w2, wt_ff2w2, CDFF, CD,
                                                           (long)CDFF * CD, (long)CD * CDFF);
  cvt_k<<<dim3(512, CL, 1), b256, 0, stream>>>(pw1_w, w_pw1, 1024L * 512, 1024L * 512,
                                               1024L * 512, 1024L * 512);
  cvt_k<<<dim3(256, CL, 1), b256, 0, stream>>>(pw2_w, w_pw2, 512L * 512, 512L * 512,
                                               512L * 512, 512L * 512);
  cvt_k<<<dim3(512, 1, 1), b256, 0, stream>>>(in_pos, posbf, 1023L * 512, 1024L * 512, 0, 0);
  dwt_k<<<dim3(62, CL), b256, 0, stream>>>(dw_w, dwT);
  qkvbias_k<<<dim3(6, CL), b256, 0, stream>>>(bq, bk, bv, qkvbias);
  copy_k<<<dim3(2048), b256, 0, stream>>>(in_x, cur);

  for (int i = 0; i < CL; ++i) {
    const u16* Wf1 = wt_ff1w1 + (long)i * CDFF * CD;
    const u16* Wf2 = wt_ff1w2 + (long)i * CD * CDFF;
    const u16* Wqk = wt_qkv + (long)i * 1536 * CD;
    const u16* Wou = wt_o + (long)i * CD * CD;
    const u16* Wps = wt_pos + (long)i * CD * CD;
    const u16* Wp1 = w_pw1 + (long)i * 1024 * CD;
    const u16* Wp2 = w_pw2 + (long)i * CD * CD;
    const u16* Wf3 = wt_ff2w1 + (long)i * CDFF * CD;
    const u16* Wf4 = wt_ff2w2 + (long)i * CD * CDFF;

    // ---- FFN1 (half residual) ----
    ln_k<0><<<dim3(1024), b256, 0, stream>>>(cur, ybf, ln1_g + i * CD, ln1_b + i * CD);
    gemm_k<128, 128, 32, 64, 64, 2><<<dim3(32, 16, 1), b256, 0, stream>>>(
        ybf, Wf1, hbf, ff1_b1 + (long)i * CDFF, 0.f, CD, CD, CDFF, CD);
    gemm_k<128, 128, 32, 64, 64, 3><<<dim3(32, 4, 1), b256, 0, stream>>>(
        hbf, Wf2, cur, ff1_b2 + i * CD, 0.5f, CDFF, CDFF, CD, CDFF);

    // ---- rel-pos MHSA (fused) ----
    ln_k<0><<<dim3(1024), b256, 0, stream>>>(cur, ybf, lnA_g + i * CD, lnA_b + i * CD);
    gemm_k<128, 128, 32, 64, 64, 1><<<dim3(32, 12, 1), b256, 0, stream>>>(
        ybf, Wqk, qkv, qkvbias + i * 1536, 0.f, CD, CD, 1536, CD);
    gemm_k<128, 128, 32, 64, 64, 0><<<dim3(8, 4, 1), b256, 0, stream>>>(
        posbf, Wps, pbf, nullptr, 0.f, CD, CD, CD, CD);
    quqv_k<<<dim3(2048), b256, 0, stream>>>(qkv, pbu + i * 512, pbv + i * 512, qu, qv);
    vtrans_k<<<dim3(8, 64), b256, 0, stream>>>(qkv, vt);
    attn_k<<<dim3(8, 64), b256, 0, stream>>>(qu, qv, qkv, pbf, vt, obf);
    gemm_k<128, 128, 32, 64, 64, 3><<<dim3(32, 4, 1), b256, 0, stream>>>(
        obf, Wou, cur, bo + i * CD, 1.0f, CD, CD, CD, CD);

    // ---- conv module ----
    ln_k<0><<<dim3(1024), b256, 0, stream>>>(cur, ybf, lnC_g + i * CD, lnC_b + i * CD);
    gemm_k<128, 128, 32, 64, 64, 4><<<dim3(32, 8, 1), b256, 0, stream>>>(
        ybf, Wp1, hbf, pw1_b + (long)i * 1024, 0.f, CD, CD, 1024, CD);
    glu_k<<<dim3(2048), b256, 0, stream>>>((const float*)hbf, ubuf);
    conv2_k<<<dim3(CT / 8, 8), b256, 0, stream>>>(ubuf, dwT + (long)i * 31 * CD,
                                                  dw_b + i * CD, cln_g + i * CD,
                                                  cln_b + i * CD, cbf);
    gemm_k<128, 128, 32, 64, 64, 3><<<dim3(32, 4, 1), b256, 0, stream>>>(
        cbf, Wp2, cur, pw2_b + i * CD, 1.0f, CD, CD, CD, CD);

    // ---- FFN2 (half residual) ----
    ln_k<0><<<dim3(1024), b256, 0, stream>>>(cur, ybf, ln2_g + i * CD, ln2_b + i * CD);
    gemm_k<128, 128, 32, 64, 64, 2><<<dim3(32, 16, 1), b256, 0, stream>>>(
        ybf, Wf3, hbf, ff2_b1 + (long)i * CDFF, 0.f, CD, CD, CDFF, CD);
    gemm_k<128, 128, 32, 64, 64, 3><<<dim3(32, 4, 1), b256, 0, stream>>>(
        hbf, Wf4, cur, ff2_b2 + i * CD, 0.5f, CDFF, CDFF, CD, CDFF);

    // ---- output LN ----
    if (i < CL - 1)
      ln_k<1><<<dim3(1024), b256, 0, stream>>>(cur, cur, lnO_g + i * CD, lnO_b + i * CD);
    else
      ln_k<1><<<dim3(1024), b256, 0, stream>>>(cur, d_out, lnO_g + i * CD, lnO_b + i * CD);
  }
}

// Round 4
// 1267.514 us; speedup vs baseline: 1.9632x; 1.1898x over previous
//
#include <hip/hip_runtime.h>

// ---------------------------------------------------------------------------
// Conformer encoder, MI355X bf16-MFMA implementation.
// Round 3: attn_k v2 — wave-independent 16-row flash attention, K/pos tiles
// double-buffered in LDS via global_load_lds (swizzled), in-register softmax,
// counted vmcnt. GLU fused into pw1 GEMM (interleaved weights). pos GEMMs
// batched into setup. quqv/glu kernels removed.
// ---------------------------------------------------------------------------

typedef unsigned short u16;
typedef unsigned int u32;
typedef __attribute__((ext_vector_type(8))) short bf16x8;
typedef __attribute__((ext_vector_type(4))) float f32x4;

#define DI __device__ __forceinline__

constexpr int CT = 512;     // sequence length T
constexpr int CD = 512;     // model dim D
constexpr int CH = 8;       // heads
constexpr int CDK = 64;     // head dim
constexpr int CDFF = 2048;  // ffn dim
constexpr int CNBT = 4096;  // B*T
constexpr int CL = 4;       // layers

DI u16 f2bf(float f) {
  u32 u = __builtin_bit_cast(u32, f);
  u = u + 0x7fffu + ((u >> 16) & 1u);
  return (u16)(u >> 16);
}
DI float bf2f(u16 h) { u32 u = ((u32)h) << 16; return __builtin_bit_cast(float, u); }
DI u32 pack2(float a, float b) { return (u32)f2bf(a) | ((u32)f2bf(b) << 16); }
DI float sigm(float x) { return 1.0f / (1.0f + __expf(-x)); }

DI f32x4 MFMA(bf16x8 a, bf16x8 b, f32x4 c) {
  return __builtin_amdgcn_mfma_f32_16x16x32_bf16(a, b, c, 0, 0, 0);
}

DI void gload16(const void* g, void* l) {
  __builtin_amdgcn_global_load_lds((const __attribute__((address_space(1))) void*)g,
                                   (__attribute__((address_space(3))) void*)l, 16, 0, 0);
}

DI float wsum(float v) {
#pragma unroll
  for (int o = 32; o > 0; o >>= 1) v += __shfl_xor(v, o, 64);
  return v;
}

// ------------------------- weight conversion -------------------------------
// fp32 [R,C] -> bf16 [C,R]  (per-z slice, separate in/out z strides)
__global__ __launch_bounds__(256) void tconv_k(const float* __restrict__ in,
                                               u16* __restrict__ out, int R, int C,
                                               long inZ, long outZ) {
  __shared__ float t[32][33];
  int c0 = blockIdx.x * 32, r0 = blockIdx.y * 32;
  const float* ip = in + (long)blockIdx.z * inZ;
  u16* op = out + (long)blockIdx.z * outZ;
#pragma unroll
  for (int i = threadIdx.y; i < 32; i += 8)
    t[i][threadIdx.x] = ip[(long)(r0 + i) * C + c0 + threadIdx.x];
  __syncthreads();
#pragma unroll
  for (int i = threadIdx.y; i < 32; i += 8)
    op[(long)(c0 + i) * R + r0 + threadIdx.x] = f2bf(t[threadIdx.x][i]);
}

// fp32 -> bf16 flat, zero-fill beyond nIn (used to pad pos_emb to 1024 rows)
__global__ __launch_bounds__(256) void cvt_k(const float* __restrict__ in,
                                             u16* __restrict__ out, long nIn, long nOut,
                                             long inZ, long outZ) {
  long i = ((long)blockIdx.x * 256 + threadIdx.x) * 4;
  if (i >= nOut) return;
  const float* ip = in + (long)blockIdx.y * inZ;
  u16* op = out + (long)blockIdx.y * outZ;
  u16 o[4];
#pragma unroll
  for (int j = 0; j < 4; ++j) {
    long idx = i + j;
    o[j] = (idx < nIn) ? f2bf(ip[idx]) : (u16)0;
  }
  uint2 st;
  st.x = (u32)o[0] | ((u32)o[1] << 16);
  st.y = (u32)o[2] | ((u32)o[3] << 16);
  *(uint2*)&op[i] = st;
}

// pw1_w [L][1024][512] f32 -> bf16 with 16-row a/g interleave:
// out row n <- orig row ((n>>4)&1 ? 512 : 0) + (n>>5)*16 + (n&15)
__global__ __launch_bounds__(256) void pwperm_k(const float* __restrict__ in,
                                                u16* __restrict__ out) {
  int l = blockIdx.y;
  long i = (long)blockIdx.x * 256 + threadIdx.x;  // quads
  long n = i >> 7;
  int c = (int)(i & 127) * 4;
  int q = (int)(n >> 4) & 1;
  long r = (q ? 512 : 0) + ((n >> 5) << 4) + (n & 15);
  const float* ip = in + ((long)l * 1024 + r) * 512 + c;
  float4 v = *(const float4*)ip;
  u16* op = out + ((long)l * 1024 + n) * 512 + c;
  uint2 st;
  st.x = pack2(v.x, v.y);
  st.y = pack2(v.z, v.w);
  *(uint2*)op = st;
}

// dw_w [L][512][31] -> wT [L][31][512] fp32
__global__ __launch_bounds__(256) void dwt_k(const float* __restrict__ in,
                                             float* __restrict__ out) {
  int l = blockIdx.y;
  int idx = blockIdx.x * 256 + threadIdx.x;
  if (idx >= 512 * 31) return;
  int k = idx >> 9, d = idx & 511;
  out[(long)l * 31 * 512 + idx] = in[(long)l * 512 * 31 + d * 31 + k];
}

__global__ __launch_bounds__(256) void qkvbias_k(const float* __restrict__ bq,
                                                 const float* __restrict__ bk,
                                                 const float* __restrict__ bv,
                                                 float* __restrict__ out) {
  int z = blockIdx.y;
  int j = blockIdx.x * 256 + threadIdx.x;
  float v;
  if (j < 512) v = bq[z * 512 + j];
  else if (j < 1024) v = bk[z * 512 + j - 512];
  else v = bv[z * 512 + j - 1024];
  out[z * 1536 + j] = v;
}

__global__ __launch_bounds__(256) void copy_k(const float* __restrict__ in,
                                              float* __restrict__ out) {
  long i = ((long)blockIdx.x * 256 + threadIdx.x) * 4;
  *(float4*)(out + i) = *(const float4*)(in + i);
}

// ------------------------------- LayerNorm ---------------------------------
template <int F32OUT>
__global__ __launch_bounds__(256) void ln_k(const float* in, void* out,
                                            const float* gw, const float* bw) {
  int tid = threadIdx.x, wid = tid >> 6, lane = tid & 63;
  long row = (long)blockIdx.x * 4 + wid;
  const float* x = in + row * CD + lane * 8;
  float4 v0 = *(const float4*)x;
  float4 v1 = *(const float4*)(x + 4);
  float s = v0.x + v0.y + v0.z + v0.w + v1.x + v1.y + v1.z + v1.w;
  float q = v0.x * v0.x + v0.y * v0.y + v0.z * v0.z + v0.w * v0.w +
            v1.x * v1.x + v1.y * v1.y + v1.z * v1.z + v1.w * v1.w;
  s = wsum(s);
  q = wsum(q);
  float mean = s * (1.0f / CD);
  float var = q * (1.0f / CD) - mean * mean;
  float rs = rsqrtf(var + 1e-5f);
  int c = lane * 8;
  float4 g0 = *(const float4*)(gw + c), g1 = *(const float4*)(gw + c + 4);
  float4 b0 = *(const float4*)(bw + c), b1 = *(const float4*)(bw + c + 4);
  float y0 = (v0.x - mean) * rs * g0.x + b0.x;
  float y1 = (v0.y - mean) * rs * g0.y + b0.y;
  float y2 = (v0.z - mean) * rs * g0.z + b0.z;
  float y3 = (v0.w - mean) * rs * g0.w + b0.w;
  float y4 = (v1.x - mean) * rs * g1.x + b1.x;
  float y5 = (v1.y - mean) * rs * g1.y + b1.y;
  float y6 = (v1.z - mean) * rs * g1.z + b1.z;
  float y7 = (v1.w - mean) * rs * g1.w + b1.w;
  if (F32OUT) {
    float* o = (float*)out + row * CD + c;
    *(float4*)o = make_float4(y0, y1, y2, y3);
    *(float4*)(o + 4) = make_float4(y4, y5, y6, y7);
  } else {
    u16* o = (u16*)out + row * CD + c;
    uint4 pk;
    pk.x = pack2(y0, y1);
    pk.y = pack2(y2, y3);
    pk.z = pack2(y4, y5);
    pk.w = pack2(y6, y7);
    *(uint4*)o = pk;
  }
}

// --------------------------------- GEMM ------------------------------------
// C[m,n] = sum_k A[m,k] * B[n,k]
// EPI: 0 store bf16 | 1 +bias bf16 | 2 +bias swish bf16 | 3 res += alpha*(v+bias)
//      4 +bias f32  | 7 GLU-packed bf16 (interleaved a/g weights, out 512-wide)
template <int BM, int BN, int BK, int WM, int WN, int EPI>
__global__ __launch_bounds__(256) void gemm_k(
    const u16* __restrict__ A, const u16* __restrict__ B, void* C,
    const float* __restrict__ bias, float alpha, int lda, int ldb, int ldc, int Kd) {
  static_assert(BK == 32, "");
  static_assert((BM / WM) * (BN / WN) == 4, "");
  __shared__ u16 ldsA[BM * BK];
  __shared__ u16 ldsB[BN * BK];
  const int tid = threadIdx.x, wid = tid >> 6, lane = tid & 63;
  const int m0 = blockIdx.x * BM, n0 = blockIdx.y * BN;
  constexpr int nWn = BN / WN;
  const int wm = wid / nWn, wn = wid % nWn;
  constexpr int FM = WM / 16, FN = WN / 16;
  const f32x4 vzero = {0.f, 0.f, 0.f, 0.f};
  f32x4 acc[FM][FN];
#pragma unroll
  for (int mi = 0; mi < FM; ++mi)
#pragma unroll
    for (int ni = 0; ni < FN; ++ni) acc[mi][ni] = vzero;

  const int ar = lane & 15, kq = (lane >> 4) * 8;
  constexpr int AR = (BM * BK * 2) / 4096;
  constexpr int BR = (BN * BK * 2) / 4096;

  for (int k0 = 0; k0 < Kd; k0 += BK) {
    __syncthreads();
#pragma unroll
    for (int r = 0; r < AR; ++r) {
      int boff = r * 4096 + tid * 16;
      int row = boff >> 6;
      int ke = (boff & 63) >> 1;
      gload16(A + (long)(m0 + row) * lda + k0 + ke,
              (char*)ldsA + r * 4096 + wid * 1024);
    }
#pragma unroll
    for (int r = 0; r < BR; ++r) {
      int boff = r * 4096 + tid * 16;
      int row = boff >> 6;
      int ke = (boff & 63) >> 1;
      gload16(B + (long)(n0 + row) * ldb + k0 + ke,
              (char*)ldsB + r * 4096 + wid * 1024);
    }
    asm volatile("s_waitcnt vmcnt(0)" ::: "memory");
    __syncthreads();
    bf16x8 af[FM], bfr[FN];
#pragma unroll
    for (int mi = 0; mi < FM; ++mi)
      af[mi] = *(const bf16x8*)&ldsA[(wm * WM + mi * 16 + ar) * BK + kq];
#pragma unroll
    for (int ni = 0; ni < FN; ++ni)
      bfr[ni] = *(const bf16x8*)&ldsB[(wn * WN + ni * 16 + ar) * BK + kq];
#pragma unroll
    for (int mi = 0; mi < FM; ++mi)
#pragma unroll
      for (int ni = 0; ni < FN; ++ni)
        acc[mi][ni] = MFMA(af[mi], bfr[ni], acc[mi][ni]);
  }

  if constexpr (EPI == 7) {
#pragma unroll
    for (int mi = 0; mi < FM; ++mi) {
      const int gmB = m0 + wm * WM + mi * 16 + (lane >> 4) * 4;
#pragma unroll
      for (int p = 0; p < FN / 2; ++p) {
        const int ucol = (n0 >> 1) + wn * (WN >> 1) + p * 16 + (lane & 15);
        float ba = bias[ucol], bg = bias[512 + ucol];
#pragma unroll
        for (int r = 0; r < 4; ++r) {
          float va = acc[mi][2 * p][r] + ba;
          float vg = acc[mi][2 * p + 1][r] + bg;
          ((u16*)C)[(long)(gmB + r) * 512 + ucol] = f2bf(va * sigm(vg));
        }
      }
    }
  } else {
#pragma unroll
    for (int mi = 0; mi < FM; ++mi) {
      const int gmB = m0 + wm * WM + mi * 16 + (lane >> 4) * 4;
#pragma unroll
      for (int ni = 0; ni < FN; ++ni) {
        const int gn = n0 + wn * WN + ni * 16 + (lane & 15);
        float bv_ = 0.f;
        if constexpr (EPI == 1 || EPI == 2 || EPI == 3 || EPI == 4) bv_ = bias[gn];
#pragma unroll
        for (int r = 0; r < 4; ++r) {
          const int gm = gmB + r;
          float v = acc[mi][ni][r];
          long idx = (long)gm * ldc + gn;
          if constexpr (EPI == 0) ((u16*)C)[idx] = f2bf(v);
          else if constexpr (EPI == 1) ((u16*)C)[idx] = f2bf(v + bv_);
          else if constexpr (EPI == 2) {
            float x = v + bv_;
            ((u16*)C)[idx] = f2bf(x * sigm(x));
          } else if constexpr (EPI == 3) {
            float* R = (float*)C;
            R[idx] += alpha * (v + bv_);
          } else if constexpr (EPI == 4) ((float*)C)[idx] = v + bv_;
        }
      }
    }
  }
}

// ---------------------------- attention helpers ----------------------------
// vt[bh][d][t] = v[b,t,h,d]  (v = cols 1024..1535 of qkv)
__global__ __launch_bounds__(256) void vtrans_k(const u16* __restrict__ qkv,
                                                u16* __restrict__ vt) {
  __shared__ u16 t[64][80];
  int tid = threadIdx.x;
  int t0 = blockIdx.x * 64;
  int bh = blockIdx.y, b = bh >> 3, h = bh & 7;
  {
    int tl = tid >> 2, dg = (tid & 3) * 16;
    const u16* src = qkv + ((long)(b * CT + t0 + tl)) * 1536 + 1024 + h * 64 + dg;
    uint4 a0 = *(const uint4*)src;
    uint4 a1 = *(const uint4*)(src + 8);
    *(uint4*)&t[tl][dg] = a0;
    *(uint4*)&t[tl][dg + 8] = a1;
  }
  __syncthreads();
  {
    int dl = tid >> 2, tg = (tid & 3) * 16;
    u16* dst = vt + ((long)bh * 64 + dl) * CT + t0 + tg;
    u16 tmp[16];
#pragma unroll
    for (int j = 0; j < 16; ++j) tmp[j] = t[tg + j][dl];
    uint4 o0, o1;
    o0.x = (u32)tmp[0] | ((u32)tmp[1] << 16);
    o0.y = (u32)tmp[2] | ((u32)tmp[3] << 16);
    o0.z = (u32)tmp[4] | ((u32)tmp[5] << 16);
    o0.w = (u32)tmp[6] | ((u32)tmp[7] << 16);
    o1.x = (u32)tmp[8] | ((u32)tmp[9] << 16);
    o1.y = (u32)tmp[10] | ((u32)tmp[11] << 16);
    o1.z = (u32)tmp[12] | ((u32)tmp[13] << 16);
    o1.w = (u32)tmp[14] | ((u32)tmp[15] << 16);
    *(uint4*)dst = o0;
    *(uint4*)(dst + 8) = o1;
  }
}

// ---------------- fused rel-pos flash attention v2 -------------------------
// block: 64 t-rows of one (b,h); 4 waves, each owns 16 rows (fully
// independent softmax). s-step 64, 8 iters. K/pos tiles double-buffered in
// LDS via global_load_lds (XOR-swizzled source), V direct from vt.
// Q(+pbu/+pbv) held in registers. Rel-shift gather is wave-local:
// jcol = sl + 15 - tlw.
__global__ __launch_bounds__(256, 2) void attn_k(
    const u16* __restrict__ qkvp, const u16* __restrict__ pball,
    const float* __restrict__ pbuL, const float* __restrict__ pbvL,
    const u16* __restrict__ vt, u16* __restrict__ out) {
  __shared__ u16 ldsK[2][64 * 64];    // [s][d] swizzled
  __shared__ u16 ldsP[2][128 * 64];   // [j][d] swizzled
  __shared__ u16 bd0s[4][16 * 80];    // per-wave bd band
  __shared__ u16 stile[4][16 * 64];   // per-wave P (swizzled rows)
  const int tid = threadIdx.x, wid = tid >> 6, lane = tid & 63;
  const int t0 = blockIdx.x * 64;
  const int bh = blockIdx.y, b = bh >> 3, h = bh & 7;
  const int fr = lane & 15, fq = lane >> 4;

  const u16* kbase = qkvp + (long)(b * CT) * 1536 + 512 + h * 64;
  const u16* pbase = pball + h * 64;
  const float* pu = pbuL + h * 64;
  const float* pv = pbvL + h * 64;

  // Q fragments for this wave's 16 rows (A-frag row = fr)
  const u16* qp = qkvp + (long)(b * CT + t0 + wid * 16 + fr) * 1536 + h * 64;
  bf16x8 qua[2], qva[2];
#pragma unroll
  for (int kk = 0; kk < 2; ++kk) {
    bf16x8 qw = *(const bf16x8*)(qp + kk * 32 + fq * 8);
    const float* bu = pu + kk * 32 + fq * 8;
    const float* bv = pv + kk * 32 + fq * 8;
#pragma unroll
    for (int j = 0; j < 8; ++j) {
      float qf = bf2f((u16)qw[j]);
      qua[kk][j] = (short)f2bf(qf + bu[j]);
      qva[kk][j] = (short)f2bf(qf + bv[j]);
    }
  }

  const f32x4 vz = {0.f, 0.f, 0.f, 0.f};
  f32x4 oacc[4] = {vz, vz, vz, vz};
  float m_run[4] = {-1e30f, -1e30f, -1e30f, -1e30f};
  float l_run[4] = {0.f, 0.f, 0.f, 0.f};
  const int jbw = (3 - wid) * 16;  // wave's bd band base

  auto stage = [&](int buf, int st) {
    int s0 = st * 64, j0 = s0 - t0 + 448;
#pragma unroll
    for (int r = 0; r < 2; ++r) {
      int c = r * 256 + tid;
      int row = c >> 3, cs = (c & 7) ^ (row & 7);
      gload16(kbase + (long)(s0 + row) * 1536 + cs * 8,
              (char*)&ldsK[buf][0] + r * 4096 + wid * 1024);
    }
#pragma unroll
    for (int r = 0; r < 4; ++r) {
      int c = r * 256 + tid;
      int row = c >> 3, cs = (c & 7) ^ (row & 7);
      gload16(pbase + (long)(j0 + row) * 2048 + cs * 8,
              (char*)&ldsP[buf][0] + r * 4096 + wid * 1024);
    }
  };

  stage(0, 0);
  int cur = 0;
  for (int st = 0; st < 8; ++st) {
    const int s0 = st * 64;
    if (st + 1 < 8) {
      stage(cur ^ 1, st + 1);
      asm volatile("s_waitcnt vmcnt(6)" ::: "memory");
    } else {
      asm volatile("s_waitcnt vmcnt(0)" ::: "memory");
    }
    __syncthreads();

    // V fragments (direct global, issue early)
    bf16x8 vb[4][2];
#pragma unroll
    for (int ni = 0; ni < 4; ++ni)
#pragma unroll
      for (int kk = 0; kk < 2; ++kk)
        vb[ni][kk] = *(const bf16x8*)&vt[((long)bh * 64 + ni * 16 + fr) * 512 +
                                         s0 + kk * 32 + fq * 8];

    // ---- AC = qu . K (from LDS) ----
    f32x4 ac[4] = {vz, vz, vz, vz};
#pragma unroll
    for (int kk = 0; kk < 2; ++kk) {
#pragma unroll
      for (int ni = 0; ni < 4; ++ni) {
        int row = ni * 16 + fr;
        bf16x8 kb = *(const bf16x8*)((const char*)&ldsK[cur][0] +
                                     ((row * 128 + kk * 64 + fq * 16) ^ ((row & 7) << 4)));
        ac[ni] = MFMA(qua[kk], kb, ac[ni]);
      }
    }
    // ---- BD band = qv . p (from LDS), 5 n-frags ----
    f32x4 bd[5] = {vz, vz, vz, vz, vz};
#pragma unroll
    for (int kk = 0; kk < 2; ++kk) {
#pragma unroll
      for (int nbi = 0; nbi < 5; ++nbi) {
        int row = jbw + nbi * 16 + fr;
        bf16x8 pb = *(const bf16x8*)((const char*)&ldsP[cur][0] +
                                     ((row * 128 + kk * 64 + fq * 16) ^ ((row & 7) << 4)));
        bd[nbi] = MFMA(qva[kk], pb, bd[nbi]);
      }
    }
#pragma unroll
    for (int nbi = 0; nbi < 5; ++nbi)
#pragma unroll
      for (int r = 0; r < 4; ++r)
        bd0s[wid][(fq * 4 + r) * 80 + nbi * 16 + fr] = f2bf(bd[nbi][r]);

    // ---- combine + in-wave online softmax ----
    float vals[4][4];
#pragma unroll
    for (int ni = 0; ni < 4; ++ni)
#pragma unroll
      for (int r = 0; r < 4; ++r) {
        int tlw = fq * 4 + r;
        int jcol = ni * 16 + fr + 15 - tlw;
        vals[ni][r] = (ac[ni][r] + bf2f(bd0s[wid][tlw * 80 + jcol])) * 0.125f;
      }
    float scf[4];
#pragma unroll
    for (int r = 0; r < 4; ++r) {
      float mx = fmaxf(fmaxf(vals[0][r], vals[1][r]), fmaxf(vals[2][r], vals[3][r]));
      mx = fmaxf(mx, __shfl_xor(mx, 1));
      mx = fmaxf(mx, __shfl_xor(mx, 2));
      mx = fmaxf(mx, __shfl_xor(mx, 4));
      mx = fmaxf(mx, __shfl_xor(mx, 8));
      float mnew = fmaxf(m_run[r], mx);
      scf[r] = __expf(m_run[r] - mnew);
      m_run[r] = mnew;
      float sum = 0.f;
#pragma unroll
      for (int ni = 0; ni < 4; ++ni) {
        float p = __expf(vals[ni][r] - mnew);
        vals[ni][r] = p;
        sum += p;
      }
      sum += __shfl_xor(sum, 1);
      sum += __shfl_xor(sum, 2);
      sum += __shfl_xor(sum, 4);
      sum += __shfl_xor(sum, 8);
      l_run[r] = l_run[r] * scf[r] + sum;
    }
    // P -> stile (swizzled rows) for PV A-frags
#pragma unroll
    for (int ni = 0; ni < 4; ++ni)
#pragma unroll
      for (int r = 0; r < 4; ++r) {
        int tlw = fq * 4 + r;
        *(u16*)((char*)&stile[wid][0] +
                (((tlw * 128) + (ni * 16 + fr) * 2) ^ ((tlw & 7) << 4))) =
            f2bf(vals[ni][r]);
      }
    // ---- rescale + PV ----
#pragma unroll
    for (int ni = 0; ni < 4; ++ni)
#pragma unroll
      for (int r = 0; r < 4; ++r) oacc[ni][r] *= scf[r];
#pragma unroll
    for (int kk = 0; kk < 2; ++kk) {
      bf16x8 pa = *(const bf16x8*)((const char*)&stile[wid][0] +
                                   ((fr * 128 + kk * 64 + fq * 16) ^ ((fr & 7) << 4)));
#pragma unroll
      for (int ni = 0; ni < 4; ++ni) oacc[ni] = MFMA(pa, vb[ni][kk], oacc[ni]);
    }
    __syncthreads();
    cur ^= 1;
  }

  float inv[4];
#pragma unroll
  for (int r = 0; r < 4; ++r) inv[r] = 1.0f / l_run[r];
#pragma unroll
  for (int ni = 0; ni < 4; ++ni)
#pragma unroll
    for (int r = 0; r < 4; ++r) {
      long row = (long)(b * CT + t0 + wid * 16 + fq * 4 + r) * CD + h * CDK;
      out[row + ni * 16 + fr] = f2bf(oacc[ni][r] * inv[r]);
    }
}

// ------------------------------ conv module --------------------------------
// depthwise conv(K=31,pad 15) + dw_b + LN(cln) + swish.
__global__ __launch_bounds__(256) void conv2_k(const u16* __restrict__ u,
                                               const float* __restrict__ wT,
                                               const float* __restrict__ wb,
                                               const float* __restrict__ cg,
                                               const float* __restrict__ cb,
                                               u16* __restrict__ out) {
  constexpr int TT = 8;
  int tid = threadIdx.x, d0 = tid * 2;
  int b = blockIdx.y, t0 = blockIdx.x * TT;
  const u16* ub = u + ((long)b * CT) * CD + d0;

  u32 strip[TT + 30];
#pragma unroll
  for (int j = 0; j < TT + 30; ++j) {
    int tt = t0 + j - 15;
    strip[j] = ((unsigned)tt < (unsigned)CT) ? *(const u32*)(ub + (long)tt * CD) : 0u;
  }
  float2 bias = *(const float2*)(wb + d0);
  float a0[TT], a1[TT];
#pragma unroll
  for (int t = 0; t < TT; ++t) { a0[t] = bias.x; a1[t] = bias.y; }
#pragma unroll
  for (int k = 0; k < 31; ++k) {
    float2 wk = *(const float2*)(wT + k * CD + d0);
#pragma unroll
    for (int t = 0; t < TT; ++t) {
      u32 pr = strip[t + k];
      a0[t] += bf2f((u16)(pr & 0xffff)) * wk.x;
      a1[t] += bf2f((u16)(pr >> 16)) * wk.y;
    }
  }
  __shared__ float redS[4][TT], redQ[4][TT];
  int wid = tid >> 6, lane = tid & 63;
#pragma unroll
  for (int t = 0; t < TT; ++t) {
    float s = a0[t] + a1[t];
    float q = a0[t] * a0[t] + a1[t] * a1[t];
    s = wsum(s);
    q = wsum(q);
    if (lane == 0) { redS[wid][t] = s; redQ[wid][t] = q; }
  }
  __syncthreads();
  float2 g2 = *(const float2*)(cg + d0);
  float2 b2 = *(const float2*)(cb + d0);
#pragma unroll
  for (int t = 0; t < TT; ++t) {
    float s = redS[0][t] + redS[1][t] + redS[2][t] + redS[3][t];
    float q = redQ[0][t] + redQ[1][t] + redQ[2][t] + redQ[3][t];
    float mean = s * (1.f / 512), var = q * (1.f / 512) - mean * mean;
    float rs = rsqrtf(var + 1e-5f);
    float y0 = (a0[t] - mean) * rs * g2.x + b2.x;
    float y1 = (a1[t] - mean) * rs * g2.y + b2.y;
    y0 = y0 * sigm(y0);
    y1 = y1 * sigm(y1);
    *(u32*)(out + ((long)(b * CT + t0 + t)) * CD + d0) = pack2(y0, y1);
  }
}

// ---------------------------------------------------------------------------
extern "C" void kernel_launch(void* const* d_in, const int* in_sizes, int n_in,
                              void* d_out, int out_size, void* d_ws, size_t ws_size,
                              hipStream_t stream) {
  const float* in_x   = (const float*)d_in[0];
  const float* in_pos = (const float*)d_in[1];
  const float* ln1_g  = (const float*)d_in[2];
  const float* ln1_b  = (const float*)d_in[3];
  const float* ff1_w1 = (const float*)d_in[4];
  const float* ff1_b1 = (const float*)d_in[5];
  const float* ff1_w2 = (const float*)d_in[6];
  const float* ff1_b2 = (const float*)d_in[7];
  const float* lnA_g  = (const float*)d_in[8];
  const float* lnA_b  = (const float*)d_in[9];
  const float* Wq     = (const float*)d_in[10];
  const float* bq     = (const float*)d_in[11];
  const float* Wk     = (const float*)d_in[12];
  const float* bk     = (const float*)d_in[13];
  const float* Wv     = (const float*)d_in[14];
  const float* bv     = (const float*)d_in[15];
  const float* Wo     = (const float*)d_in[16];
  const float* bo     = (const float*)d_in[17];
  const float* Wpos   = (const float*)d_in[18];
  const float* pbu    = (const float*)d_in[19];
  const float* pbv    = (const float*)d_in[20];
  const float* lnC_g  = (const float*)d_in[21];
  const float* lnC_b  = (const float*)d_in[22];
  const float* pw1_w  = (const float*)d_in[23];
  const float* pw1_b  = (const float*)d_in[24];
  const float* dw_w   = (const float*)d_in[25];
  const float* dw_b   = (const float*)d_in[26];
  const float* cln_g  = (const float*)d_in[27];
  const float* cln_b  = (const float*)d_in[28];
  const float* pw2_w  = (const float*)d_in[29];
  const float* pw2_b  = (const float*)d_in[30];
  const float* ln2_g  = (const float*)d_in[31];
  const float* ln2_b  = (const float*)d_in[32];
  const float* ff2_w1 = (const float*)d_in[33];
  const float* ff2_b1 = (const float*)d_in[34];
  const float* ff2_w2 = (const float*)d_in[35];
  const float* ff2_b2 = (const float*)d_in[36];
  const float* lnO_g  = (const float*)d_in[37];
  const float* lnO_b  = (const float*)d_in[38];
  (void)in_sizes; (void)n_in; (void)out_size; (void)ws_size;

  char* ws = (char*)d_ws;
  size_t off = 0;
  auto alloc = [&](size_t bytes) -> void* {
    off = (off + 255) & ~(size_t)255;
    void* p = ws + off;
    off += bytes;
    return p;
  };

  // weights (bf16, [N,K] layout)
  u16* wt_ff1w1 = (u16*)alloc((size_t)CL * CDFF * CD * 2);
  u16* wt_ff1w2 = (u16*)alloc((size_t)CL * CD * CDFF * 2);
  u16* wt_qkv   = (u16*)alloc((size_t)CL * 1536 * CD * 2);
  u16* wt_o     = (u16*)alloc((size_t)CL * CD * CD * 2);
  u16* wt_pos   = (u16*)alloc((size_t)CL * CD * CD * 2);
  u16* w_pw1p   = (u16*)alloc((size_t)CL * 1024 * CD * 2);
  u16* w_pw2    = (u16*)alloc((size_t)CL * CD * CD * 2);
  u16* wt_ff2w1 = (u16*)alloc((size_t)CL * CDFF * CD * 2);
  u16* wt_ff2w2 = (u16*)alloc((size_t)CL * CD * CDFF * 2);
  float* qkvbias = (float*)alloc((size_t)CL * 1536 * 4);
  u16* posbf = (u16*)alloc((size_t)1024 * CD * 2);
  float* dwT = (float*)alloc((size_t)CL * 31 * CD * 4);
  u16* pbf_all = (u16*)alloc((size_t)1024 * 2048 * 2);
  // activations
  float* cur = (float*)alloc((size_t)CNBT * CD * 4);
  u16* ybf   = (u16*)alloc((size_t)CNBT * CD * 2);
  u16* qkv   = (u16*)alloc((size_t)CNBT * 1536 * 2);
  u16* hbf   = (u16*)alloc((size_t)CNBT * CDFF * 2);
  u16* vt    = (u16*)alloc((size_t)64 * CDK * CT * 2);
  u16* obf   = (u16*)alloc((size_t)CNBT * CD * 2);
  u16* ubuf  = (u16*)alloc((size_t)CNBT * CD * 2);
  u16* cbf   = (u16*)alloc((size_t)CNBT * CD * 2);

  dim3 b256(256);
  dim3 tb(32, 8);

  // ---- setup: weight conversion (every call; deterministic) ----
  tconv_k<<<dim3(CDFF / 32, CD / 32, CL), tb, 0, stream>>>(ff1_w1, wt_ff1w1, CD, CDFF,
                                                           (long)CD * CDFF, (long)CDFF * CD);
  tconv_k<<<dim3(CD / 32, CDFF / 32, CL), tb, 0, stream>>>(ff1_w2, wt_ff1w2, CDFF, CD,
                                                           (long)CDFF * CD, (long)CD * CDFF);
  tconv_k<<<dim3(CD / 32, CD / 32, CL), tb, 0, stream>>>(Wq, wt_qkv, CD, CD,
                                                         (long)CD * CD, 1536L * CD);
  tconv_k<<<dim3(CD / 32, CD / 32, CL), tb, 0, stream>>>(Wk, wt_qkv + 512 * 512, CD, CD,
                                                         (long)CD * CD, 1536L * CD);
  tconv_k<<<dim3(CD / 32, CD / 32, CL), tb, 0, stream>>>(Wv, wt_qkv + 1024 * 512, CD, CD,
                                                         (long)CD * CD, 1536L * CD);
  tconv_k<<<dim3(CD / 32, CD / 32, CL), tb, 0, stream>>>(Wo, wt_o, CD, CD,
                                                         (long)CD * CD, (long)CD * CD);
  tconv_k<<<dim3(CD / 32, CD / 32, CL), tb, 0, stream>>>(Wpos, wt_pos, CD, CD,
                                                         (long)CD * CD, (long)CD * CD);
  tconv_k<<<dim3(CDFF / 32, CD / 32, CL), tb, 0, stream>>>(ff2_w1, wt_ff2w1, CD, CDFF,
                                                           (long)CD * CDFF, (long)CDFF * CD);
  tconv_k<<<dim3(CD / 32, CDFF / 32, CL), tb, 0, stream>>>(ff2_w2, wt_ff2w2, CDFF, CD,
                                                           (long)CDFF * CD, (long)CD * CDFF);
  pwperm_k<<<dim3(512, CL), b256, 0, stream>>>(pw1_w, w_pw1p);
  cvt_k<<<dim3(256, CL, 1), b256, 0, stream>>>(pw2_w, w_pw2, 512L * 512, 512L * 512,
                                               512L * 512, 512L * 512);
  cvt_k<<<dim3(512, 1, 1), b256, 0, stream>>>(in_pos, posbf, 1023L * 512, 1024L * 512, 0, 0);
  dwt_k<<<dim3(62, CL), b256, 0, stream>>>(dw_w, dwT);
  qkvbias_k<<<dim3(6, CL), b256, 0, stream>>>(bq, bk, bv, qkvbias);
  copy_k<<<dim3(2048), b256, 0, stream>>>(in_x, cur);
  // all-layer pos projection: pbf_all[j][l*512+c]
  gemm_k<128, 128, 32, 64, 64, 0><<<dim3(8, 16, 1), b256, 0, stream>>>(
      posbf, wt_pos, pbf_all, nullptr, 0.f, CD, CD, 2048, CD);

  for (int i = 0; i < CL; ++i) {
    const u16* Wf1 = wt_ff1w1 + (long)i * CDFF * CD;
    const u16* Wf2 = wt_ff1w2 + (long)i * CD * CDFF;
    const u16* Wqk = wt_qkv + (long)i * 1536 * CD;
    const u16* Wou = wt_o + (long)i * CD * CD;
    const u16* Wp1 = w_pw1p + (long)i * 1024 * CD;
    const u16* Wp2 = w_pw2 + (long)i * CD * CD;
    const u16* Wf3 = wt_ff2w1 + (long)i * CDFF * CD;
    const u16* Wf4 = wt_ff2w2 + (long)i * CD * CDFF;

    // ---- FFN1 (half residual) ----
    ln_k<0><<<dim3(1024), b256, 0, stream>>>(cur, ybf, ln1_g + i * CD, ln1_b + i * CD);
    gemm_k<128, 128, 32, 64, 64, 2><<<dim3(32, 16, 1), b256, 0, stream>>>(
        ybf, Wf1, hbf, ff1_b1 + (long)i * CDFF, 0.f, CD, CD, CDFF, CD);
    gemm_k<128, 128, 32, 64, 64, 3><<<dim3(32, 4, 1), b256, 0, stream>>>(
        hbf, Wf2, cur, ff1_b2 + i * CD, 0.5f, CDFF, CDFF, CD, CDFF);

    // ---- rel-pos MHSA (fused) ----
    ln_k<0><<<dim3(1024), b256, 0, stream>>>(cur, ybf, lnA_g + i * CD, lnA_b + i * CD);
    gemm_k<128, 128, 32, 64, 64, 1><<<dim3(32, 12, 1), b256, 0, stream>>>(
        ybf, Wqk, qkv, qkvbias + i * 1536, 0.f, CD, CD, 1536, CD);
    vtrans_k<<<dim3(8, 64), b256, 0, stream>>>(qkv, vt);
    attn_k<<<dim3(8, 64), b256, 0, stream>>>(qkv, pbf_all + i * 512, pbu + i * 512,
                                             pbv + i * 512, vt, obf);
    gemm_k<128, 128, 32, 64, 64, 3><<<dim3(32, 4, 1), b256, 0, stream>>>(
        obf, Wou, cur, bo + i * CD, 1.0f, CD, CD, CD, CD);

    // ---- conv module ----
    ln_k<0><<<dim3(1024), b256, 0, stream>>>(cur, ybf, lnC_g + i * CD, lnC_b + i * CD);
    gemm_k<128, 128, 32, 64, 64, 7><<<dim3(32, 8, 1), b256, 0, stream>>>(
        ybf, Wp1, ubuf, pw1_b + (long)i * 1024, 0.f, CD, CD, 512, CD);
    conv2_k<<<dim3(CT / 8, 8), b256, 0, stream>>>(ubuf, dwT + (long)i * 31 * CD,
                                                  dw_b + i * CD, cln_g + i * CD,
                                                  cln_b + i * CD, cbf);
    gemm_k<128, 128, 32, 64, 64, 3><<<dim3(32, 4, 1), b256, 0, stream>>>(
        cbf, Wp2, cur, pw2_b + i * CD, 1.0f, CD, CD, CD, CD);

    // ---- FFN2 (half residual) ----
    ln_k<0><<<dim3(1024), b256, 0, stream>>>(cur, ybf, ln2_g + i * CD, ln2_b + i * CD);
    gemm_k<128, 128, 32, 64, 64, 2><<<dim3(32, 16, 1), b256, 0, stream>>>(
        ybf, Wf3, hbf, ff2_b1 + (long)i * CDFF, 0.f, CD, CD, CDFF, CD);
    gemm_k<128, 128, 32, 64, 64, 3><<<dim3(32, 4, 1), b256, 0, stream>>>(
        hbf, Wf4, cur, ff2_b2 + i * CD, 0.5f, CDFF, CDFF, CD, CDFF);

    // ---- output LN ----
    if (i < CL - 1)
      ln_k<1><<<dim3(1024), b256, 0, stream>>>(cur, cur, lnO_g + i * CD, lnO_b + i * CD);
    else
      ln_k<1><<<dim3(1024), b256, 0, stream>>>(cur, d_out, lnO_g + i * CD, lnO_b + i * CD);
  }
}

// Round 5
// 816.484 us; speedup vs baseline: 3.0477x; 1.5524x over previous
//
#include <hip/hip_runtime.h>

// ---------------------------------------------------------------------------
// Conformer encoder, MI355X bf16-MFMA implementation.
// Round 4: gemm2_k — 64x64 tile, BK=64, double-buffered LDS (2-phase
// schedule), XOR-swizzled staging/reads, split-K(atomic) for K=2048 residual
// GEMMs. All GEMMs now run >=2 blocks/CU (was 128 blocks on 256 CUs).
// ---------------------------------------------------------------------------

typedef unsigned short u16;
typedef unsigned int u32;
typedef __attribute__((ext_vector_type(8))) short bf16x8;
typedef __attribute__((ext_vector_type(4))) float f32x4;

#define DI __device__ __forceinline__

constexpr int CT = 512;     // sequence length T
constexpr int CD = 512;     // model dim D
constexpr int CH = 8;       // heads
constexpr int CDK = 64;     // head dim
constexpr int CDFF = 2048;  // ffn dim
constexpr int CNBT = 4096;  // B*T
constexpr int CL = 4;       // layers

DI u16 f2bf(float f) {
  u32 u = __builtin_bit_cast(u32, f);
  u = u + 0x7fffu + ((u >> 16) & 1u);
  return (u16)(u >> 16);
}
DI float bf2f(u16 h) { u32 u = ((u32)h) << 16; return __builtin_bit_cast(float, u); }
DI u32 pack2(float a, float b) { return (u32)f2bf(a) | ((u32)f2bf(b) << 16); }
DI float sigm(float x) { return 1.0f / (1.0f + __expf(-x)); }

DI f32x4 MFMA(bf16x8 a, bf16x8 b, f32x4 c) {
  return __builtin_amdgcn_mfma_f32_16x16x32_bf16(a, b, c, 0, 0, 0);
}

DI void gload16(const void* g, void* l) {
  __builtin_amdgcn_global_load_lds((const __attribute__((address_space(1))) void*)g,
                                   (__attribute__((address_space(3))) void*)l, 16, 0, 0);
}

DI float wsum(float v) {
#pragma unroll
  for (int o = 32; o > 0; o >>= 1) v += __shfl_xor(v, o, 64);
  return v;
}

// ------------------------- weight conversion -------------------------------
// fp32 [R,C] -> bf16 [C,R]  (per-z slice, separate in/out z strides)
__global__ __launch_bounds__(256) void tconv_k(const float* __restrict__ in,
                                               u16* __restrict__ out, int R, int C,
                                               long inZ, long outZ) {
  __shared__ float t[32][33];
  int c0 = blockIdx.x * 32, r0 = blockIdx.y * 32;
  const float* ip = in + (long)blockIdx.z * inZ;
  u16* op = out + (long)blockIdx.z * outZ;
#pragma unroll
  for (int i = threadIdx.y; i < 32; i += 8)
    t[i][threadIdx.x] = ip[(long)(r0 + i) * C + c0 + threadIdx.x];
  __syncthreads();
#pragma unroll
  for (int i = threadIdx.y; i < 32; i += 8)
    op[(long)(c0 + i) * R + r0 + threadIdx.x] = f2bf(t[threadIdx.x][i]);
}

// fp32 -> bf16 flat, zero-fill beyond nIn (used to pad pos_emb to 1024 rows)
__global__ __launch_bounds__(256) void cvt_k(const float* __restrict__ in,
                                             u16* __restrict__ out, long nIn, long nOut,
                                             long inZ, long outZ) {
  long i = ((long)blockIdx.x * 256 + threadIdx.x) * 4;
  if (i >= nOut) return;
  const float* ip = in + (long)blockIdx.y * inZ;
  u16* op = out + (long)blockIdx.y * outZ;
  u16 o[4];
#pragma unroll
  for (int j = 0; j < 4; ++j) {
    long idx = i + j;
    o[j] = (idx < nIn) ? f2bf(ip[idx]) : (u16)0;
  }
  uint2 st;
  st.x = (u32)o[0] | ((u32)o[1] << 16);
  st.y = (u32)o[2] | ((u32)o[3] << 16);
  *(uint2*)&op[i] = st;
}

// pw1_w [L][1024][512] f32 -> bf16 with 16-row a/g interleave:
// out row n <- orig row ((n>>4)&1 ? 512 : 0) + (n>>5)*16 + (n&15)
__global__ __launch_bounds__(256) void pwperm_k(const float* __restrict__ in,
                                                u16* __restrict__ out) {
  int l = blockIdx.y;
  long i = (long)blockIdx.x * 256 + threadIdx.x;  // quads
  long n = i >> 7;
  int c = (int)(i & 127) * 4;
  int q = (int)(n >> 4) & 1;
  long r = (q ? 512 : 0) + ((n >> 5) << 4) + (n & 15);
  const float* ip = in + ((long)l * 1024 + r) * 512 + c;
  float4 v = *(const float4*)ip;
  u16* op = out + ((long)l * 1024 + n) * 512 + c;
  uint2 st;
  st.x = pack2(v.x, v.y);
  st.y = pack2(v.z, v.w);
  *(uint2*)op = st;
}

// dw_w [L][512][31] -> wT [L][31][512] fp32
__global__ __launch_bounds__(256) void dwt_k(const float* __restrict__ in,
                                             float* __restrict__ out) {
  int l = blockIdx.y;
  int idx = blockIdx.x * 256 + threadIdx.x;
  if (idx >= 512 * 31) return;
  int k = idx >> 9, d = idx & 511;
  out[(long)l * 31 * 512 + idx] = in[(long)l * 512 * 31 + d * 31 + k];
}

__global__ __launch_bounds__(256) void qkvbias_k(const float* __restrict__ bq,
                                                 const float* __restrict__ bk,
                                                 const float* __restrict__ bv,
                                                 float* __restrict__ out) {
  int z = blockIdx.y;
  int j = blockIdx.x * 256 + threadIdx.x;
  float v;
  if (j < 512) v = bq[z * 512 + j];
  else if (j < 1024) v = bk[z * 512 + j - 512];
  else v = bv[z * 512 + j - 1024];
  out[z * 1536 + j] = v;
}

__global__ __launch_bounds__(256) void copy_k(const float* __restrict__ in,
                                              float* __restrict__ out) {
  long i = ((long)blockIdx.x * 256 + threadIdx.x) * 4;
  *(float4*)(out + i) = *(const float4*)(in + i);
}

// ------------------------------- LayerNorm ---------------------------------
template <int F32OUT>
__global__ __launch_bounds__(256) void ln_k(const float* in, void* out,
                                            const float* gw, const float* bw) {
  int tid = threadIdx.x, wid = tid >> 6, lane = tid & 63;
  long row = (long)blockIdx.x * 4 + wid;
  const float* x = in + row * CD + lane * 8;
  float4 v0 = *(const float4*)x;
  float4 v1 = *(const float4*)(x + 4);
  float s = v0.x + v0.y + v0.z + v0.w + v1.x + v1.y + v1.z + v1.w;
  float q = v0.x * v0.x + v0.y * v0.y + v0.z * v0.z + v0.w * v0.w +
            v1.x * v1.x + v1.y * v1.y + v1.z * v1.z + v1.w * v1.w;
  s = wsum(s);
  q = wsum(q);
  float mean = s * (1.0f / CD);
  float var = q * (1.0f / CD) - mean * mean;
  float rs = rsqrtf(var + 1e-5f);
  int c = lane * 8;
  float4 g0 = *(const float4*)(gw + c), g1 = *(const float4*)(gw + c + 4);
  float4 b0 = *(const float4*)(bw + c), b1 = *(const float4*)(bw + c + 4);
  float y0 = (v0.x - mean) * rs * g0.x + b0.x;
  float y1 = (v0.y - mean) * rs * g0.y + b0.y;
  float y2 = (v0.z - mean) * rs * g0.z + b0.z;
  float y3 = (v0.w - mean) * rs * g0.w + b0.w;
  float y4 = (v1.x - mean) * rs * g1.x + b1.x;
  float y5 = (v1.y - mean) * rs * g1.y + b1.y;
  float y6 = (v1.z - mean) * rs * g1.z + b1.z;
  float y7 = (v1.w - mean) * rs * g1.w + b1.w;
  if (F32OUT) {
    float* o = (float*)out + row * CD + c;
    *(float4*)o = make_float4(y0, y1, y2, y3);
    *(float4*)(o + 4) = make_float4(y4, y5, y6, y7);
  } else {
    u16* o = (u16*)out + row * CD + c;
    uint4 pk;
    pk.x = pack2(y0, y1);
    pk.y = pack2(y2, y3);
    pk.z = pack2(y4, y5);
    pk.w = pack2(y6, y7);
    *(uint4*)o = pk;
  }
}

// --------------------------------- GEMM v2 ---------------------------------
// C[m,n] = sum_k A[m,k] * B[n,k]   (A [M,K], B [N,K] row-major, bf16)
// 64x64 tile, BK=64, 4 waves of 32x32. Double-buffered swizzled LDS,
// 2-phase schedule (stage next || compute cur, one vmcnt(0)+barrier per tile).
// EPI: 0 store bf16 | 1 +bias bf16 | 2 +bias swish bf16
//      3 res += alpha*(v+bias) (atomic when SPLITK>1; bias from z==0 chunk)
//      7 GLU-packed bf16 (interleaved a/g weights, out 512-wide)
template <int EPI, int SPLITK>
__global__ __launch_bounds__(256, 2) void gemm2_k(
    const u16* __restrict__ A, const u16* __restrict__ B, void* C,
    const float* __restrict__ bias, float alpha, int lda, int ldb, int ldc, int Kd) {
  __shared__ u16 lds[2][2][64 * 64];  // [buf][A/B][row*64]
  const int tid = threadIdx.x, wid = tid >> 6, lane = tid & 63;
  const int m0 = blockIdx.x * 64, n0 = blockIdx.y * 64;
  const int wm = wid >> 1, wn = wid & 1;
  const int fr = lane & 15, fq = lane >> 4;
  const f32x4 vz = {0.f, 0.f, 0.f, 0.f};
  f32x4 acc[2][2] = {{vz, vz}, {vz, vz}};

  const int Kc = Kd / SPLITK;
  const int kb0 = (SPLITK > 1) ? blockIdx.z * Kc : 0;
  const int nK = Kc / 64;

  auto stage = [&](int buf, int kt) {
    const int k0 = kb0 + kt * 64;
#pragma unroll
    for (int r = 0; r < 2; ++r) {
      int bi = r * 4096 + tid * 16;
      int row = bi >> 7;
      int ch = ((bi >> 4) & 7) ^ (row & 7);  // inverse swizzle on source
      gload16(A + (long)(m0 + row) * lda + k0 + ch * 8,
              (char*)&lds[buf][0][0] + r * 4096 + wid * 1024);
      gload16(B + (long)(n0 + row) * ldb + k0 + ch * 8,
              (char*)&lds[buf][1][0] + r * 4096 + wid * 1024);
    }
  };

  stage(0, 0);
  asm volatile("s_waitcnt vmcnt(0)" ::: "memory");
  __syncthreads();
  int buf = 0;
  for (int kt = 0; kt < nK; ++kt) {
    if (kt + 1 < nK) stage(buf ^ 1, kt + 1);
    bf16x8 af[2][2], bfv[2][2];
#pragma unroll
    for (int ks = 0; ks < 2; ++ks) {
      int ch = ks * 4 + fq;
#pragma unroll
      for (int i = 0; i < 2; ++i) {
        int arow = wm * 32 + i * 16 + fr;
        af[ks][i] = *(const bf16x8*)((const char*)&lds[buf][0][0] + arow * 128 +
                                     ((ch ^ (arow & 7)) << 4));
        int brow = wn * 32 + i * 16 + fr;
        bfv[ks][i] = *(const bf16x8*)((const char*)&lds[buf][1][0] + brow * 128 +
                                      ((ch ^ (brow & 7)) << 4));
      }
    }
#pragma unroll
    for (int ks = 0; ks < 2; ++ks)
#pragma unroll
      for (int mi = 0; mi < 2; ++mi)
#pragma unroll
        for (int ni = 0; ni < 2; ++ni)
          acc[mi][ni] = MFMA(af[ks][mi], bfv[ks][ni], acc[mi][ni]);
    asm volatile("s_waitcnt vmcnt(0)" ::: "memory");
    __syncthreads();
    buf ^= 1;
  }

  if constexpr (EPI == 7) {
    const int ucol = (n0 >> 1) + wn * 16 + fr;
    float ba = bias[ucol], bg = bias[512 + ucol];
#pragma unroll
    for (int mi = 0; mi < 2; ++mi) {
      const int gmB = m0 + wm * 32 + mi * 16 + fq * 4;
#pragma unroll
      for (int r = 0; r < 4; ++r) {
        float va = acc[mi][0][r] + ba;
        float vg = acc[mi][1][r] + bg;
        ((u16*)C)[(long)(gmB + r) * 512 + ucol] = f2bf(va * sigm(vg));
      }
    }
  } else {
#pragma unroll
    for (int mi = 0; mi < 2; ++mi) {
      const int gmB = m0 + wm * 32 + mi * 16 + fq * 4;
#pragma unroll
      for (int ni = 0; ni < 2; ++ni) {
        const int gn = n0 + wn * 32 + ni * 16 + fr;
        float bv_ = 0.f;
        if constexpr (EPI == 1 || EPI == 2 || EPI == 3) bv_ = bias[gn];
#pragma unroll
        for (int r = 0; r < 4; ++r) {
          const int gm = gmB + r;
          float v = acc[mi][ni][r];
          long idx = (long)gm * ldc + gn;
          if constexpr (EPI == 0) ((u16*)C)[idx] = f2bf(v);
          else if constexpr (EPI == 1) ((u16*)C)[idx] = f2bf(v + bv_);
          else if constexpr (EPI == 2) {
            float x = v + bv_;
            ((u16*)C)[idx] = f2bf(x * sigm(x));
          } else if constexpr (EPI == 3) {
            float* R = (float*)C;
            if constexpr (SPLITK > 1) {
              float add = alpha * (v + (blockIdx.z == 0 ? bv_ : 0.f));
              atomicAdd(&R[idx], add);
            } else {
              R[idx] += alpha * (v + bv_);
            }
          }
        }
      }
    }
  }
}

// ---------------------------- attention helpers ----------------------------
// vt[bh][d][t] = v[b,t,h,d]  (v = cols 1024..1535 of qkv)
__global__ __launch_bounds__(256) void vtrans_k(const u16* __restrict__ qkv,
                                                u16* __restrict__ vt) {
  __shared__ u16 t[64][80];
  int tid = threadIdx.x;
  int t0 = blockIdx.x * 64;
  int bh = blockIdx.y, b = bh >> 3, h = bh & 7;
  {
    int tl = tid >> 2, dg = (tid & 3) * 16;
    const u16* src = qkv + ((long)(b * CT + t0 + tl)) * 1536 + 1024 + h * 64 + dg;
    uint4 a0 = *(const uint4*)src;
    uint4 a1 = *(const uint4*)(src + 8);
    *(uint4*)&t[tl][dg] = a0;
    *(uint4*)&t[tl][dg + 8] = a1;
  }
  __syncthreads();
  {
    int dl = tid >> 2, tg = (tid & 3) * 16;
    u16* dst = vt + ((long)bh * 64 + dl) * CT + t0 + tg;
    u16 tmp[16];
#pragma unroll
    for (int j = 0; j < 16; ++j) tmp[j] = t[tg + j][dl];
    uint4 o0, o1;
    o0.x = (u32)tmp[0] | ((u32)tmp[1] << 16);
    o0.y = (u32)tmp[2] | ((u32)tmp[3] << 16);
    o0.z = (u32)tmp[4] | ((u32)tmp[5] << 16);
    o0.w = (u32)tmp[6] | ((u32)tmp[7] << 16);
    o1.x = (u32)tmp[8] | ((u32)tmp[9] << 16);
    o1.y = (u32)tmp[10] | ((u32)tmp[11] << 16);
    o1.z = (u32)tmp[12] | ((u32)tmp[13] << 16);
    o1.w = (u32)tmp[14] | ((u32)tmp[15] << 16);
    *(uint4*)dst = o0;
    *(uint4*)(dst + 8) = o1;
  }
}

// ---------------- fused rel-pos flash attention v2 -------------------------
__global__ __launch_bounds__(256, 2) void attn_k(
    const u16* __restrict__ qkvp, const u16* __restrict__ pball,
    const float* __restrict__ pbuL, const float* __restrict__ pbvL,
    const u16* __restrict__ vt, u16* __restrict__ out) {
  __shared__ u16 ldsK[2][64 * 64];    // [s][d] swizzled
  __shared__ u16 ldsP[2][128 * 64];   // [j][d] swizzled
  __shared__ u16 bd0s[4][16 * 80];    // per-wave bd band
  __shared__ u16 stile[4][16 * 64];   // per-wave P (swizzled rows)
  const int tid = threadIdx.x, wid = tid >> 6, lane = tid & 63;
  const int t0 = blockIdx.x * 64;
  const int bh = blockIdx.y, b = bh >> 3, h = bh & 7;
  const int fr = lane & 15, fq = lane >> 4;

  const u16* kbase = qkvp + (long)(b * CT) * 1536 + 512 + h * 64;
  const u16* pbase = pball + h * 64;
  const float* pu = pbuL + h * 64;
  const float* pv = pbvL + h * 64;

  const u16* qp = qkvp + (long)(b * CT + t0 + wid * 16 + fr) * 1536 + h * 64;
  bf16x8 qua[2], qva[2];
#pragma unroll
  for (int kk = 0; kk < 2; ++kk) {
    bf16x8 qw = *(const bf16x8*)(qp + kk * 32 + fq * 8);
    const float* bu = pu + kk * 32 + fq * 8;
    const float* bv = pv + kk * 32 + fq * 8;
#pragma unroll
    for (int j = 0; j < 8; ++j) {
      float qf = bf2f((u16)qw[j]);
      qua[kk][j] = (short)f2bf(qf + bu[j]);
      qva[kk][j] = (short)f2bf(qf + bv[j]);
    }
  }

  const f32x4 vz = {0.f, 0.f, 0.f, 0.f};
  f32x4 oacc[4] = {vz, vz, vz, vz};
  float m_run[4] = {-1e30f, -1e30f, -1e30f, -1e30f};
  float l_run[4] = {0.f, 0.f, 0.f, 0.f};
  const int jbw = (3 - wid) * 16;

  auto stage = [&](int buf, int st) {
    int s0 = st * 64, j0 = s0 - t0 + 448;
#pragma unroll
    for (int r = 0; r < 2; ++r) {
      int c = r * 256 + tid;
      int row = c >> 3, cs = (c & 7) ^ (row & 7);
      gload16(kbase + (long)(s0 + row) * 1536 + cs * 8,
              (char*)&ldsK[buf][0] + r * 4096 + wid * 1024);
    }
#pragma unroll
    for (int r = 0; r < 4; ++r) {
      int c = r * 256 + tid;
      int row = c >> 3, cs = (c & 7) ^ (row & 7);
      gload16(pbase + (long)(j0 + row) * 2048 + cs * 8,
              (char*)&ldsP[buf][0] + r * 4096 + wid * 1024);
    }
  };

  stage(0, 0);
  int cur = 0;
  for (int st = 0; st < 8; ++st) {
    const int s0 = st * 64;
    if (st + 1 < 8) {
      stage(cur ^ 1, st + 1);
      asm volatile("s_waitcnt vmcnt(6)" ::: "memory");
    } else {
      asm volatile("s_waitcnt vmcnt(0)" ::: "memory");
    }
    __syncthreads();

    bf16x8 vb[4][2];
#pragma unroll
    for (int ni = 0; ni < 4; ++ni)
#pragma unroll
      for (int kk = 0; kk < 2; ++kk)
        vb[ni][kk] = *(const bf16x8*)&vt[((long)bh * 64 + ni * 16 + fr) * 512 +
                                         s0 + kk * 32 + fq * 8];

    f32x4 ac[4] = {vz, vz, vz, vz};
#pragma unroll
    for (int kk = 0; kk < 2; ++kk) {
#pragma unroll
      for (int ni = 0; ni < 4; ++ni) {
        int row = ni * 16 + fr;
        bf16x8 kb = *(const bf16x8*)((const char*)&ldsK[cur][0] +
                                     ((row * 128 + kk * 64 + fq * 16) ^ ((row & 7) << 4)));
        ac[ni] = MFMA(qua[kk], kb, ac[ni]);
      }
    }
    f32x4 bd[5] = {vz, vz, vz, vz, vz};
#pragma unroll
    for (int kk = 0; kk < 2; ++kk) {
#pragma unroll
      for (int nbi = 0; nbi < 5; ++nbi) {
        int row = jbw + nbi * 16 + fr;
        bf16x8 pb = *(const bf16x8*)((const char*)&ldsP[cur][0] +
                                     ((row * 128 + kk * 64 + fq * 16) ^ ((row & 7) << 4)));
        bd[nbi] = MFMA(qva[kk], pb, bd[nbi]);
      }
    }
#pragma unroll
    for (int nbi = 0; nbi < 5; ++nbi)
#pragma unroll
      for (int r = 0; r < 4; ++r)
        bd0s[wid][(fq * 4 + r) * 80 + nbi * 16 + fr] = f2bf(bd[nbi][r]);

    float vals[4][4];
#pragma unroll
    for (int ni = 0; ni < 4; ++ni)
#pragma unroll
      for (int r = 0; r < 4; ++r) {
        int tlw = fq * 4 + r;
        int jcol = ni * 16 + fr + 15 - tlw;
        vals[ni][r] = (ac[ni][r] + bf2f(bd0s[wid][tlw * 80 + jcol])) * 0.125f;
      }
    float scf[4];
#pragma unroll
    for (int r = 0; r < 4; ++r) {
      float mx = fmaxf(fmaxf(vals[0][r], vals[1][r]), fmaxf(vals[2][r], vals[3][r]));
      mx = fmaxf(mx, __shfl_xor(mx, 1));
      mx = fmaxf(mx, __shfl_xor(mx, 2));
      mx = fmaxf(mx, __shfl_xor(mx, 4));
      mx = fmaxf(mx, __shfl_xor(mx, 8));
      float mnew = fmaxf(m_run[r], mx);
      scf[r] = __expf(m_run[r] - mnew);
      m_run[r] = mnew;
      float sum = 0.f;
#pragma unroll
      for (int ni = 0; ni < 4; ++ni) {
        float p = __expf(vals[ni][r] - mnew);
        vals[ni][r] = p;
        sum += p;
      }
      sum += __shfl_xor(sum, 1);
      sum += __shfl_xor(sum, 2);
      sum += __shfl_xor(sum, 4);
      sum += __shfl_xor(sum, 8);
      l_run[r] = l_run[r] * scf[r] + sum;
    }
#pragma unroll
    for (int ni = 0; ni < 4; ++ni)
#pragma unroll
      for (int r = 0; r < 4; ++r) {
        int tlw = fq * 4 + r;
        *(u16*)((char*)&stile[wid][0] +
                (((tlw * 128) + (ni * 16 + fr) * 2) ^ ((tlw & 7) << 4))) =
            f2bf(vals[ni][r]);
      }
#pragma unroll
    for (int ni = 0; ni < 4; ++ni)
#pragma unroll
      for (int r = 0; r < 4; ++r) oacc[ni][r] *= scf[r];
#pragma unroll
    for (int kk = 0; kk < 2; ++kk) {
      bf16x8 pa = *(const bf16x8*)((const char*)&stile[wid][0] +
                                   ((fr * 128 + kk * 64 + fq * 16) ^ ((fr & 7) << 4)));
#pragma unroll
      for (int ni = 0; ni < 4; ++ni) oacc[ni] = MFMA(pa, vb[ni][kk], oacc[ni]);
    }
    __syncthreads();
    cur ^= 1;
  }

  float inv[4];
#pragma unroll
  for (int r = 0; r < 4; ++r) inv[r] = 1.0f / l_run[r];
#pragma unroll
  for (int ni = 0; ni < 4; ++ni)
#pragma unroll
    for (int r = 0; r < 4; ++r) {
      long row = (long)(b * CT + t0 + wid * 16 + fq * 4 + r) * CD + h * CDK;
      out[row + ni * 16 + fr] = f2bf(oacc[ni][r] * inv[r]);
    }
}

// ------------------------------ conv module --------------------------------
// depthwise conv(K=31,pad 15) + dw_b + LN(cln) + swish.
__global__ __launch_bounds__(256) void conv2_k(const u16* __restrict__ u,
                                               const float* __restrict__ wT,
                                               const float* __restrict__ wb,
                                               const float* __restrict__ cg,
                                               const float* __restrict__ cb,
                                               u16* __restrict__ out) {
  constexpr int TT = 8;
  int tid = threadIdx.x, d0 = tid * 2;
  int b = blockIdx.y, t0 = blockIdx.x * TT;
  const u16* ub = u + ((long)b * CT) * CD + d0;

  u32 strip[TT + 30];
#pragma unroll
  for (int j = 0; j < TT + 30; ++j) {
    int tt = t0 + j - 15;
    strip[j] = ((unsigned)tt < (unsigned)CT) ? *(const u32*)(ub + (long)tt * CD) : 0u;
  }
  float2 bias = *(const float2*)(wb + d0);
  float a0[TT], a1[TT];
#pragma unroll
  for (int t = 0; t < TT; ++t) { a0[t] = bias.x; a1[t] = bias.y; }
#pragma unroll
  for (int k = 0; k < 31; ++k) {
    float2 wk = *(const float2*)(wT + k * CD + d0);
#pragma unroll
    for (int t = 0; t < TT; ++t) {
      u32 pr = strip[t + k];
      a0[t] += bf2f((u16)(pr & 0xffff)) * wk.x;
      a1[t] += bf2f((u16)(pr >> 16)) * wk.y;
    }
  }
  __shared__ float redS[4][TT], redQ[4][TT];
  int wid = tid >> 6, lane = tid & 63;
#pragma unroll
  for (int t = 0; t < TT; ++t) {
    float s = a0[t] + a1[t];
    float q = a0[t] * a0[t] + a1[t] * a1[t];
    s = wsum(s);
    q = wsum(q);
    if (lane == 0) { redS[wid][t] = s; redQ[wid][t] = q; }
  }
  __syncthreads();
  float2 g2 = *(const float2*)(cg + d0);
  float2 b2 = *(const float2*)(cb + d0);
#pragma unroll
  for (int t = 0; t < TT; ++t) {
    float s = redS[0][t] + redS[1][t] + redS[2][t] + redS[3][t];
    float q = redQ[0][t] + redQ[1][t] + redQ[2][t] + redQ[3][t];
    float mean = s * (1.f / 512), var = q * (1.f / 512) - mean * mean;
    float rs = rsqrtf(var + 1e-5f);
    float y0 = (a0[t] - mean) * rs * g2.x + b2.x;
    float y1 = (a1[t] - mean) * rs * g2.y + b2.y;
    y0 = y0 * sigm(y0);
    y1 = y1 * sigm(y1);
    *(u32*)(out + ((long)(b * CT + t0 + t)) * CD + d0) = pack2(y0, y1);
  }
}

// ---------------------------------------------------------------------------
extern "C" void kernel_launch(void* const* d_in, const int* in_sizes, int n_in,
                              void* d_out, int out_size, void* d_ws, size_t ws_size,
                              hipStream_t stream) {
  const float* in_x   = (const float*)d_in[0];
  const float* in_pos = (const float*)d_in[1];
  const float* ln1_g  = (const float*)d_in[2];
  const float* ln1_b  = (const float*)d_in[3];
  const float* ff1_w1 = (const float*)d_in[4];
  const float* ff1_b1 = (const float*)d_in[5];
  const float* ff1_w2 = (const float*)d_in[6];
  const float* ff1_b2 = (const float*)d_in[7];
  const float* lnA_g  = (const float*)d_in[8];
  const float* lnA_b  = (const float*)d_in[9];
  const float* Wq     = (const float*)d_in[10];
  const float* bq     = (const float*)d_in[11];
  const float* Wk     = (const float*)d_in[12];
  const float* bk     = (const float*)d_in[13];
  const float* Wv     = (const float*)d_in[14];
  const float* bv     = (const float*)d_in[15];
  const float* Wo     = (const float*)d_in[16];
  const float* bo     = (const float*)d_in[17];
  const float* Wpos   = (const float*)d_in[18];
  const float* pbu    = (const float*)d_in[19];
  const float* pbv    = (const float*)d_in[20];
  const float* lnC_g  = (const float*)d_in[21];
  const float* lnC_b  = (const float*)d_in[22];
  const float* pw1_w  = (const float*)d_in[23];
  const float* pw1_b  = (const float*)d_in[24];
  const float* dw_w   = (const float*)d_in[25];
  const float* dw_b   = (const float*)d_in[26];
  const float* cln_g  = (const float*)d_in[27];
  const float* cln_b  = (const float*)d_in[28];
  const float* pw2_w  = (const float*)d_in[29];
  const float* pw2_b  = (const float*)d_in[30];
  const float* ln2_g  = (const float*)d_in[31];
  const float* ln2_b  = (const float*)d_in[32];
  const float* ff2_w1 = (const float*)d_in[33];
  const float* ff2_b1 = (const float*)d_in[34];
  const float* ff2_w2 = (const float*)d_in[35];
  const float* ff2_b2 = (const float*)d_in[36];
  const float* lnO_g  = (const float*)d_in[37];
  const float* lnO_b  = (const float*)d_in[38];
  (void)in_sizes; (void)n_in; (void)out_size; (void)ws_size;

  char* ws = (char*)d_ws;
  size_t off = 0;
  auto alloc = [&](size_t bytes) -> void* {
    off = (off + 255) & ~(size_t)255;
    void* p = ws + off;
    off += bytes;
    return p;
  };

  // weights (bf16, [N,K] layout)
  u16* wt_ff1w1 = (u16*)alloc((size_t)CL * CDFF * CD * 2);
  u16* wt_ff1w2 = (u16*)alloc((size_t)CL * CD * CDFF * 2);
  u16* wt_qkv   = (u16*)alloc((size_t)CL * 1536 * CD * 2);
  u16* wt_o     = (u16*)alloc((size_t)CL * CD * CD * 2);
  u16* wt_pos   = (u16*)alloc((size_t)CL * CD * CD * 2);
  u16* w_pw1p   = (u16*)alloc((size_t)CL * 1024 * CD * 2);
  u16* w_pw2    = (u16*)alloc((size_t)CL * CD * CD * 2);
  u16* wt_ff2w1 = (u16*)alloc((size_t)CL * CDFF * CD * 2);
  u16* wt_ff2w2 = (u16*)alloc((size_t)CL * CD * CDFF * 2);
  float* qkvbias = (float*)alloc((size_t)CL * 1536 * 4);
  u16* posbf = (u16*)alloc((size_t)1024 * CD * 2);
  float* dwT = (float*)alloc((size_t)CL * 31 * CD * 4);
  u16* pbf_all = (u16*)alloc((size_t)1024 * 2048 * 2);
  // activations
  float* cur = (float*)alloc((size_t)CNBT * CD * 4);
  u16* ybf   = (u16*)alloc((size_t)CNBT * CD * 2);
  u16* qkv   = (u16*)alloc((size_t)CNBT * 1536 * 2);
  u16* hbf   = (u16*)alloc((size_t)CNBT * CDFF * 2);
  u16* vt    = (u16*)alloc((size_t)64 * CDK * CT * 2);
  u16* obf   = (u16*)alloc((size_t)CNBT * CD * 2);
  u16* ubuf  = (u16*)alloc((size_t)CNBT * CD * 2);
  u16* cbf   = (u16*)alloc((size_t)CNBT * CD * 2);

  dim3 b256(256);
  dim3 tb(32, 8);

  // ---- setup: weight conversion (every call; deterministic) ----
  tconv_k<<<dim3(CDFF / 32, CD / 32, CL), tb, 0, stream>>>(ff1_w1, wt_ff1w1, CD, CDFF,
                                                           (long)CD * CDFF, (long)CDFF * CD);
  tconv_k<<<dim3(CD / 32, CDFF / 32, CL), tb, 0, stream>>>(ff1_w2, wt_ff1w2, CDFF, CD,
                                                           (long)CDFF * CD, (long)CD * CDFF);
  tconv_k<<<dim3(CD / 32, CD / 32, CL), tb, 0, stream>>>(Wq, wt_qkv, CD, CD,
                                                         (long)CD * CD, 1536L * CD);
  tconv_k<<<dim3(CD / 32, CD / 32, CL), tb, 0, stream>>>(Wk, wt_qkv + 512 * 512, CD, CD,
                                                         (long)CD * CD, 1536L * CD);
  tconv_k<<<dim3(CD / 32, CD / 32, CL), tb, 0, stream>>>(Wv, wt_qkv + 1024 * 512, CD, CD,
                                                         (long)CD * CD, 1536L * CD);
  tconv_k<<<dim3(CD / 32, CD / 32, CL), tb, 0, stream>>>(Wo, wt_o, CD, CD,
                                                         (long)CD * CD, (long)CD * CD);
  tconv_k<<<dim3(CD / 32, CD / 32, CL), tb, 0, stream>>>(Wpos, wt_pos, CD, CD,
                                                         (long)CD * CD, (long)CD * CD);
  tconv_k<<<dim3(CDFF / 32, CD / 32, CL), tb, 0, stream>>>(ff2_w1, wt_ff2w1, CD, CDFF,
                                                           (long)CD * CDFF, (long)CDFF * CD);
  tconv_k<<<dim3(CD / 32, CDFF / 32, CL), tb, 0, stream>>>(ff2_w2, wt_ff2w2, CDFF, CD,
                                                           (long)CDFF * CD, (long)CD * CDFF);
  pwperm_k<<<dim3(512, CL), b256, 0, stream>>>(pw1_w, w_pw1p);
  cvt_k<<<dim3(256, CL, 1), b256, 0, stream>>>(pw2_w, w_pw2, 512L * 512, 512L * 512,
                                               512L * 512, 512L * 512);
  cvt_k<<<dim3(512, 1, 1), b256, 0, stream>>>(in_pos, posbf, 1023L * 512, 1024L * 512, 0, 0);
  dwt_k<<<dim3(62, CL), b256, 0, stream>>>(dw_w, dwT);
  qkvbias_k<<<dim3(6, CL), b256, 0, stream>>>(bq, bk, bv, qkvbias);
  copy_k<<<dim3(2048), b256, 0, stream>>>(in_x, cur);
  // all-layer pos projection: pbf_all[j][l*512+c]
  gemm2_k<0, 1><<<dim3(16, 32, 1), b256, 0, stream>>>(
      posbf, wt_pos, pbf_all, nullptr, 0.f, CD, CD, 2048, CD);

  for (int i = 0; i < CL; ++i) {
    const u16* Wf1 = wt_ff1w1 + (long)i * CDFF * CD;
    const u16* Wf2 = wt_ff1w2 + (long)i * CD * CDFF;
    const u16* Wqk = wt_qkv + (long)i * 1536 * CD;
    const u16* Wou = wt_o + (long)i * CD * CD;
    const u16* Wp1 = w_pw1p + (long)i * 1024 * CD;
    const u16* Wp2 = w_pw2 + (long)i * CD * CD;
    const u16* Wf3 = wt_ff2w1 + (long)i * CDFF * CD;
    const u16* Wf4 = wt_ff2w2 + (long)i * CD * CDFF;

    // ---- FFN1 (half residual) ----
    ln_k<0><<<dim3(1024), b256, 0, stream>>>(cur, ybf, ln1_g + i * CD, ln1_b + i * CD);
    gemm2_k<2, 1><<<dim3(64, 32, 1), b256, 0, stream>>>(
        ybf, Wf1, hbf, ff1_b1 + (long)i * CDFF, 0.f, CD, CD, CDFF, CD);
    gemm2_k<3, 2><<<dim3(64, 8, 2), b256, 0, stream>>>(
        hbf, Wf2, cur, ff1_b2 + i * CD, 0.5f, CDFF, CDFF, CD, CDFF);

    // ---- rel-pos MHSA (fused) ----
    ln_k<0><<<dim3(1024), b256, 0, stream>>>(cur, ybf, lnA_g + i * CD, lnA_b + i * CD);
    gemm2_k<1, 1><<<dim3(64, 24, 1), b256, 0, stream>>>(
        ybf, Wqk, qkv, qkvbias + i * 1536, 0.f, CD, CD, 1536, CD);
    vtrans_k<<<dim3(8, 64), b256, 0, stream>>>(qkv, vt);
    attn_k<<<dim3(8, 64), b256, 0, stream>>>(qkv, pbf_all + i * 512, pbu + i * 512,
                                             pbv + i * 512, vt, obf);
    gemm2_k<3, 1><<<dim3(64, 8, 1), b256, 0, stream>>>(
        obf, Wou, cur, bo + i * CD, 1.0f, CD, CD, CD, CD);

    // ---- conv module ----
    ln_k<0><<<dim3(1024), b256, 0, stream>>>(cur, ybf, lnC_g + i * CD, lnC_b + i * CD);
    gemm2_k<7, 1><<<dim3(64, 16, 1), b256, 0, stream>>>(
        ybf, Wp1, ubuf, pw1_b + (long)i * 1024, 0.f, CD, CD, 512, CD);
    conv2_k<<<dim3(CT / 8, 8), b256, 0, stream>>>(ubuf, dwT + (long)i * 31 * CD,
                                                  dw_b + i * CD, cln_g + i * CD,
                                                  cln_b + i * CD, cbf);
    gemm2_k<3, 1><<<dim3(64, 8, 1), b256, 0, stream>>>(
        cbf, Wp2, cur, pw2_b + i * CD, 1.0f, CD, CD, CD, CD);

    // ---- FFN2 (half residual) ----
    ln_k<0><<<dim3(1024), b256, 0, stream>>>(cur, ybf, ln2_g + i * CD, ln2_b + i * CD);
    gemm2_k<2, 1><<<dim3(64, 32, 1), b256, 0, stream>>>(
        ybf, Wf3, hbf, ff2_b1 + (long)i * CDFF, 0.f, CD, CD, CDFF, CD);
    gemm2_k<3, 2><<<dim3(64, 8, 2), b256, 0, stream>>>(
        hbf, Wf4, cur, ff2_b2 + i * CD, 0.5f, CDFF, CDFF, CD, CDFF);

    // ---- output LN ----
    if (i < CL - 1)
      ln_k<1><<<dim3(1024), b256, 0, stream>>>(cur, cur, lnO_g + i * CD, lnO_b + i * CD);
    else
      ln_k<1><<<dim3(1024), b256, 0, stream>>>(cur, d_out, lnO_g + i * CD, lnO_b + i * CD);
  }
}